// Round 2
// baseline (3615.112 us; speedup 1.0000x reference)
//
#include <hip/hip_runtime.h>
#include <hip/hip_bf16.h>

// Problem dims (fixed by reference)
#define B_ 8
#define S_ 2048
#define E_ 128
#define CC_ 256
#define H_ 256
#define NH_ 8
#define HD_ 32
#define KW_ 7

// ---------------------------------------------------------------------------
// Kernel 1: conv1d (K=7, pad 3) over S, E=128 in-ch, CC=256 out-ch, + bias + relu
// block = 256 threads (one per out-channel), handles 16 consecutive s positions
// ---------------------------------------------------------------------------
__global__ __launch_bounds__(256) void conv_relu_kernel(
    const float* __restrict__ x, const float* __restrict__ cw,
    const float* __restrict__ cb, float* __restrict__ h)
{
    const int TS = 16;
    __shared__ float xl[TS + 6][E_];   // s0-3 .. s0+TS+2
    int blk = blockIdx.x;
    int b  = blk / (S_ / TS);
    int s0 = (blk % (S_ / TS)) * TS;
    int tid = threadIdx.x;

    for (int idx = tid; idx < (TS + 6) * E_; idx += 256) {
        int row = idx / E_, e = idx % E_;
        int pos = s0 - 3 + row;
        float v = 0.f;
        if (pos >= 0 && pos < S_) v = x[((size_t)b * S_ + pos) * E_ + e];
        xl[row][e] = v;
    }
    __syncthreads();

    int cc = tid;
    float bias = cb[cc];
    float acc[TS];
#pragma unroll
    for (int i = 0; i < TS; i++) acc[i] = bias;

    const float* wp = cw + (size_t)cc * E_ * KW_;
    for (int e = 0; e < E_; e++) {
#pragma unroll
        for (int kk = 0; kk < KW_; kk++) {
            float w = wp[e * KW_ + kk];
#pragma unroll
            for (int s = 0; s < TS; s++) acc[s] += w * xl[s + kk][e];  // broadcast read
        }
    }
    for (int s = 0; s < TS; s++) {
        float v = acc[s] > 0.f ? acc[s] : 0.f;
        h[((size_t)b * S_ + s0 + s) * CC_ + cc] = v;
    }
}

// ---------------------------------------------------------------------------
// Kernel 2: penalty vector pvec(B,S) + valid lengths. Runtime-detects mask dtype.
// ---------------------------------------------------------------------------
__global__ __launch_bounds__(256) void penalty_kernel(
    const void* __restrict__ mask, const float* __restrict__ gamma_p,
    const float* __restrict__ std_p, float* __restrict__ pvec,
    int* __restrict__ lenv)
{
    __shared__ int cnt[256];
    int b = blockIdx.x, tid = threadIdx.x;

    // element-width detection: mask[0][0] is always valid (lengths >= S/2)
    uint32_t w0 = ((const uint32_t*)mask)[0];
    int mode = 0;                         // int32 (documented mapping for bool)
    if (w0 == 0x01010101u) mode = 1;      // uint8
    else if (w0 == 0x3F803F80u) mode = 2; // bf16 pair
    else if (w0 == 0x3F800000u) mode = 3; // float32

    int c = 0;
    for (int s = tid; s < S_; s += 256) {
        bool vv;
        size_t i = (size_t)b * S_ + s;
        if (mode == 0)      vv = ((const int*)mask)[i] != 0;
        else if (mode == 1) vv = ((const unsigned char*)mask)[i] != 0;
        else if (mode == 2) vv = (((const unsigned short*)mask)[i] & 0x7FFFu) != 0;
        else                vv = ((const float*)mask)[i] != 0.f;
        c += vv ? 1 : 0;
    }
    cnt[tid] = c;
    __syncthreads();
    for (int off = 128; off > 0; off >>= 1) {
        if (tid < off) cnt[tid] += cnt[tid + off];
        __syncthreads();
    }
    int L = cnt[0];
    if (tid == 0) lenv[b] = L;

    float Lf = (float)L;
    float gamma = gamma_p[0];
    float sd = std_p[0];
    sd = fminf(fmaxf(sd, 0.01f), 0.5f);
    float scale = expf(gamma) - 1.f;
    float inv2s2 = 1.f / (2.f * sd * sd);
    for (int s = tid; s < S_; s += 256) {
        float np = (s + 1.f) / (Lf + 1.f);
        float e = np - 0.5f;
        float base = expf(-(e * e) * inv2s2);
        pvec[(size_t)b * S_ + s] = (s < L) ? base * scale : 0.f;
    }
}

// ---------------------------------------------------------------------------
// Kernel 3: q/k/v projections. h(B,S,256) @ W(256,256) + b, x3.
// Stores (B,NH,S,HD) layout for attention.
// ---------------------------------------------------------------------------
__global__ __launch_bounds__(256) void qkv_kernel(
    const float* __restrict__ h,
    const float* __restrict__ wq, const float* __restrict__ bq,
    const float* __restrict__ wk, const float* __restrict__ bk,
    const float* __restrict__ wv, const float* __restrict__ bv,
    float* __restrict__ qo, float* __restrict__ ko, float* __restrict__ vo)
{
    const int TS = 16;
    __shared__ float hl[TS][CC_];
    int blk = blockIdx.x;
    int b  = blk / (S_ / TS);
    int s0 = (blk % (S_ / TS)) * TS;
    int tid = threadIdx.x;

    for (int idx = tid; idx < TS * CC_; idx += 256)
        hl[idx / CC_][idx % CC_] = h[((size_t)b * S_ + s0 + idx / CC_) * CC_ + idx % CC_];
    __syncthreads();

    int col = tid, n = col / HD_, d = col % HD_;
    const float* Ws[3] = {wq, wk, wv};
    const float* Bs[3] = {bq, bk, bv};
    float* Os[3] = {qo, ko, vo};
#pragma unroll
    for (int m = 0; m < 3; m++) {
        float acc[TS];
        float bias = Bs[m][col];
#pragma unroll
        for (int i = 0; i < TS; i++) acc[i] = bias;
        const float* W = Ws[m];
        for (int kk = 0; kk < CC_; kk++) {
            float w = W[kk * H_ + col];   // coalesced across threads
#pragma unroll
            for (int r = 0; r < TS; r++) acc[r] += hl[r][kk] * w;  // broadcast read
        }
        float* O = Os[m];
        for (int r = 0; r < TS; r++)
            O[(((size_t)b * NH_ + n) * S_ + s0 + r) * HD_ + d] = acc[r];
    }
}

// ---------------------------------------------------------------------------
// Kernel 4: flash-style attention with Gaussian penalty + prefix mask.
// block = (b, head, 16 q-rows), K/V tiles of 128 in LDS, online softmax.
// ---------------------------------------------------------------------------
__global__ __launch_bounds__(256) void attn_kernel(
    const float* __restrict__ q, const float* __restrict__ k, const float* __restrict__ v,
    const float* __restrict__ pvec, const int* __restrict__ lenv, float* __restrict__ ctx)
{
    const int TQ = 16, TK = 128;
    __shared__ float kl[TK][HD_ + 1];   // [key][dim], padded
    __shared__ float vl[HD_][TK + 1];   // transposed: [dim][key], padded
    __shared__ float sl[TQ][TK + 1];    // scores/probs
    __shared__ float cx[TQ][HD_];       // running ctx
    __shared__ float pk[TK];
    __shared__ float mrow[TQ], lrow[TQ], arow[TQ];
    __shared__ float red[TQ][17];

    int blk = blockIdx.x;
    int qb = blk % (S_ / TQ);
    int n  = (blk / (S_ / TQ)) % NH_;
    int b  = blk / ((S_ / TQ) * NH_);
    int q0 = qb * TQ;
    int tid = threadIdx.x;
    int L = lenv[b];

    int r = tid & 15;  // this thread's fixed q-row for the score phase
    float qreg[HD_];
    {
        const float* qp = q + (((size_t)b * NH_ + n) * S_ + q0 + r) * HD_;
#pragma unroll
        for (int d = 0; d < HD_; d++) qreg[d] = qp[d];
    }
    float pvq = pvec[(size_t)b * S_ + q0 + r];
    bool vq = (q0 + r) < L;

    for (int i = tid; i < TQ * HD_; i += 256) cx[i / HD_][i % HD_] = 0.f;
    if (tid < TQ) { mrow[tid] = -1e30f; lrow[tid] = 0.f; }
    __syncthreads();

    const float* kbase = k + ((size_t)b * NH_ + n) * (size_t)S_ * HD_;
    const float* vbase = v + ((size_t)b * NH_ + n) * (size_t)S_ * HD_;

    for (int kt = 0; kt < S_ / TK; kt++) {
        int k0 = kt * TK;
        for (int idx = tid; idx < TK * HD_; idx += 256) {
            int kk = idx / HD_, d = idx % HD_;
            float kvv = kbase[(size_t)(k0 + kk) * HD_ + d];
            float vvv = vbase[(size_t)(k0 + kk) * HD_ + d];
            kl[kk][d] = kvv;
            vl[d][kk] = vvv;
        }
        if (tid < TK) pk[tid] = pvec[(size_t)b * S_ + k0 + tid];
        __syncthreads();

        // scores: 16q x 128k, thread covers (r, kk = tid>>4 + 16j)
#pragma unroll
        for (int j = 0; j < 8; j++) {
            int kk = (tid >> 4) + 16 * j;
            float s = 0.f;
#pragma unroll
            for (int d = 0; d < HD_; d++) s += qreg[d] * kl[kk][d];
            int kg = k0 + kk;
            bool vk = kg < L;
            float pen = (vq && vk) ? 0.5f * (pvq + pk[kk]) : 0.f;
            s = s * 0.17677669529663687f - pen;  // 1/sqrt(32)
            if (!vk) s = -1e10f;
            sl[r][kk] = s;
        }
        __syncthreads();

        // row max (partial then final)
        {
            int rr = tid >> 4, c = tid & 15;
            float mx = -1e30f;
#pragma unroll
            for (int i = 0; i < 8; i++) mx = fmaxf(mx, sl[rr][c * 8 + i]);
            red[rr][c] = mx;
        }
        __syncthreads();
        if (tid < TQ) {
            float mx = -1e30f;
#pragma unroll
            for (int c = 0; c < 16; c++) mx = fmaxf(mx, red[tid][c]);
            float mn = fmaxf(mrow[tid], mx);
            arow[tid] = __expf(mrow[tid] - mn);
            mrow[tid] = mn;
        }
        __syncthreads();

        // p = exp(s - m), row partial sums
        {
            int rr = tid >> 4, c = tid & 15;
            float m = mrow[rr];
            float sum = 0.f;
#pragma unroll
            for (int i = 0; i < 8; i++) {
                float p = __expf(sl[rr][c * 8 + i] - m);
                sl[rr][c * 8 + i] = p;
                sum += p;
            }
            red[rr][c] = sum;
        }
        __syncthreads();
        if (tid < TQ) {
            float sum = 0.f;
#pragma unroll
            for (int c = 0; c < 16; c++) sum += red[tid][c];
            lrow[tid] = lrow[tid] * arow[tid] + sum;
        }

        // ctx update: 16x32 elements, 2 per thread
#pragma unroll
        for (int i = 0; i < 2; i++) {
            int idx = tid + 256 * i;
            int rr = idx / HD_, d = idx % HD_;
            float c = cx[rr][d] * arow[rr];
            for (int kk = 0; kk < TK; kk++) c += sl[rr][kk] * vl[d][kk];
            cx[rr][d] = c;
        }
        __syncthreads();
    }

    // normalize + write ctx (B,S,H) layout for the fc
#pragma unroll
    for (int i = 0; i < 2; i++) {
        int idx = tid + 256 * i;
        int rr = idx / HD_, d = idx % HD_;
        ctx[((size_t)b * S_ + q0 + rr) * H_ + n * HD_ + d] = cx[rr][d] / lrow[rr];
    }
}

// ---------------------------------------------------------------------------
// Kernel 5: fc (ctx @ fc_w + fc_b) + residual + LayerNorm, f32 out
// ---------------------------------------------------------------------------
__global__ __launch_bounds__(256) void fc_ln_kernel(
    const float* __restrict__ ctxv, const float* __restrict__ h,
    const float* __restrict__ fw, const float* __restrict__ fb,
    const float* __restrict__ g, const float* __restrict__ bb,
    float* __restrict__ out)
{
    const int TS = 16;
    __shared__ float cl[TS][CC_];
    int blk = blockIdx.x;
    int b  = blk / (S_ / TS);
    int s0 = (blk % (S_ / TS)) * TS;
    int tid = threadIdx.x;

    for (int idx = tid; idx < TS * CC_; idx += 256)
        cl[idx / CC_][idx % CC_] = ctxv[((size_t)b * S_ + s0 + idx / CC_) * H_ + idx % CC_];
    __syncthreads();

    int col = tid;
    float acc[TS];
    float bias = fb[col];
#pragma unroll
    for (int i = 0; i < TS; i++) acc[i] = bias;
    for (int kk = 0; kk < H_; kk++) {
        float w = fw[kk * CC_ + col];  // coalesced
#pragma unroll
        for (int r2 = 0; r2 < TS; r2++) acc[r2] += cl[r2][kk] * w;
    }
    __syncthreads();
    // z = h + out -> overwrite LDS
    for (int r2 = 0; r2 < TS; r2++)
        cl[r2][col] = acc[r2] + h[((size_t)b * S_ + s0 + r2) * CC_ + col];
    __syncthreads();

    // LayerNorm: wave per 4 rows
    int wid = tid >> 6, lane = tid & 63;
    for (int r2 = wid * 4; r2 < wid * 4 + 4; r2++) {
        float z0 = cl[r2][lane], z1 = cl[r2][lane + 64];
        float z2 = cl[r2][lane + 128], z3 = cl[r2][lane + 192];
        float s = z0 + z1 + z2 + z3;
#pragma unroll
        for (int off = 32; off > 0; off >>= 1) s += __shfl_xor(s, off, 64);
        float mu = s * (1.f / 256.f);
        float d0 = z0 - mu, d1 = z1 - mu, d2 = z2 - mu, d3 = z3 - mu;
        float vs = d0 * d0 + d1 * d1 + d2 * d2 + d3 * d3;
#pragma unroll
        for (int off = 32; off > 0; off >>= 1) vs += __shfl_xor(vs, off, 64);
        float inv = rsqrtf(vs * (1.f / 256.f) + 1e-5f);
        size_t ro = ((size_t)b * S_ + s0 + r2) * CC_;
#pragma unroll
        for (int i = 0; i < 4; i++) {
            int c = lane + 64 * i;
            float dz = (i == 0) ? d0 : (i == 1) ? d1 : (i == 2) ? d2 : d3;
            out[ro + c] = dz * inv * g[c] + bb[c];
        }
    }
}

// ---------------------------------------------------------------------------
extern "C" void kernel_launch(void* const* d_in, const int* in_sizes, int n_in,
                              void* d_out, int out_size, void* d_ws, size_t ws_size,
                              hipStream_t stream)
{
    const float* x      = (const float*)d_in[0];
    const void*  mask   = d_in[1];
    const float* conv_w = (const float*)d_in[2];
    const float* conv_b = (const float*)d_in[3];
    const float* wq     = (const float*)d_in[4];
    const float* bq     = (const float*)d_in[5];
    const float* wk     = (const float*)d_in[6];
    const float* bk     = (const float*)d_in[7];
    const float* wv     = (const float*)d_in[8];
    const float* bv     = (const float*)d_in[9];
    const float* fc_w   = (const float*)d_in[10];
    const float* fc_b   = (const float*)d_in[11];
    const float* ln_g   = (const float*)d_in[12];
    const float* ln_b   = (const float*)d_in[13];
    const float* gamma  = (const float*)d_in[14];
    const float* stdp   = (const float*)d_in[15];

    char* ws = (char*)d_ws;
    const size_t SZ = (size_t)B_ * S_ * CC_ * sizeof(float);  // 16 MiB
    float* h    = (float*)(ws);
    float* q    = (float*)(ws + SZ);
    float* k    = (float*)(ws + 2 * SZ);
    float* v    = (float*)(ws + 3 * SZ);
    float* ctx  = (float*)(ws + 4 * SZ);
    float* pvec = (float*)(ws + 5 * SZ);
    int*   lenv = (int*)(ws + 5 * SZ + (size_t)B_ * S_ * sizeof(float));

    conv_relu_kernel<<<B_ * S_ / 16, 256, 0, stream>>>(x, conv_w, conv_b, h);
    penalty_kernel<<<B_, 256, 0, stream>>>(mask, gamma, stdp, pvec, lenv);
    qkv_kernel<<<B_ * S_ / 16, 256, 0, stream>>>(h, wq, bq, wk, bk, wv, bv, q, k, v);
    attn_kernel<<<B_ * NH_ * (S_ / 16), 256, 0, stream>>>(q, k, v, pvec, lenv, ctx);
    fc_ln_kernel<<<B_ * S_ / 16, 256, 0, stream>>>(ctx, h, fc_w, fc_b, ln_g, ln_b,
                                                   (float*)d_out);
}

// Round 3
// 514.164 us; speedup vs baseline: 7.0311x; 7.0311x over previous
//
#include <hip/hip_runtime.h>
#include <hip/hip_bf16.h>

// Problem dims (fixed by reference)
#define B_ 8
#define S_ 2048
#define E_ 128
#define CC_ 256
#define H_ 256
#define NH_ 8
#define HD_ 32
#define KW_ 7

typedef __attribute__((ext_vector_type(8))) short bf16x8;
typedef __attribute__((ext_vector_type(4))) float f32x4;

// ---------------------------------------------------------------------------
// Kernel 1: conv1d (K=7, pad 3) + bias + relu  (unchanged from round 2)
// ---------------------------------------------------------------------------
__global__ __launch_bounds__(256) void conv_relu_kernel(
    const float* __restrict__ x, const float* __restrict__ cw,
    const float* __restrict__ cb, float* __restrict__ h)
{
    const int TS = 16;
    __shared__ float xl[TS + 6][E_];
    int blk = blockIdx.x;
    int b  = blk / (S_ / TS);
    int s0 = (blk % (S_ / TS)) * TS;
    int tid = threadIdx.x;

    for (int idx = tid; idx < (TS + 6) * E_; idx += 256) {
        int row = idx / E_, e = idx % E_;
        int pos = s0 - 3 + row;
        float v = 0.f;
        if (pos >= 0 && pos < S_) v = x[((size_t)b * S_ + pos) * E_ + e];
        xl[row][e] = v;
    }
    __syncthreads();

    int cc = tid;
    float bias = cb[cc];
    float acc[TS];
#pragma unroll
    for (int i = 0; i < TS; i++) acc[i] = bias;

    const float* wp = cw + (size_t)cc * E_ * KW_;
    for (int e = 0; e < E_; e++) {
#pragma unroll
        for (int kk = 0; kk < KW_; kk++) {
            float w = wp[e * KW_ + kk];
#pragma unroll
            for (int s = 0; s < TS; s++) acc[s] += w * xl[s + kk][e];
        }
    }
    for (int s = 0; s < TS; s++) {
        float v = acc[s] > 0.f ? acc[s] : 0.f;
        h[((size_t)b * S_ + s0 + s) * CC_ + cc] = v;
    }
}

// ---------------------------------------------------------------------------
// Kernel 2: penalty vector pvec(B,S) + valid lengths (unchanged)
// ---------------------------------------------------------------------------
__global__ __launch_bounds__(256) void penalty_kernel(
    const void* __restrict__ mask, const float* __restrict__ gamma_p,
    const float* __restrict__ std_p, float* __restrict__ pvec,
    int* __restrict__ lenv)
{
    __shared__ int cnt[256];
    int b = blockIdx.x, tid = threadIdx.x;

    uint32_t w0 = ((const uint32_t*)mask)[0];
    int mode = 0;
    if (w0 == 0x01010101u) mode = 1;
    else if (w0 == 0x3F803F80u) mode = 2;
    else if (w0 == 0x3F800000u) mode = 3;

    int c = 0;
    for (int s = tid; s < S_; s += 256) {
        bool vv;
        size_t i = (size_t)b * S_ + s;
        if (mode == 0)      vv = ((const int*)mask)[i] != 0;
        else if (mode == 1) vv = ((const unsigned char*)mask)[i] != 0;
        else if (mode == 2) vv = (((const unsigned short*)mask)[i] & 0x7FFFu) != 0;
        else                vv = ((const float*)mask)[i] != 0.f;
        c += vv ? 1 : 0;
    }
    cnt[tid] = c;
    __syncthreads();
    for (int off = 128; off > 0; off >>= 1) {
        if (tid < off) cnt[tid] += cnt[tid + off];
        __syncthreads();
    }
    int L = cnt[0];
    if (tid == 0) lenv[b] = L;

    float Lf = (float)L;
    float gamma = gamma_p[0];
    float sd = std_p[0];
    sd = fminf(fmaxf(sd, 0.01f), 0.5f);
    float scale = expf(gamma) - 1.f;
    float inv2s2 = 1.f / (2.f * sd * sd);
    for (int s = tid; s < S_; s += 256) {
        float np = (s + 1.f) / (Lf + 1.f);
        float e = np - 0.5f;
        float base = expf(-(e * e) * inv2s2);
        pvec[(size_t)b * S_ + s] = (s < L) ? base * scale : 0.f;
    }
}

// ---------------------------------------------------------------------------
// Kernel 3: q/k/v projections -> bf16 outputs in (B,NH,S,HD) layout
// ---------------------------------------------------------------------------
__global__ __launch_bounds__(256) void qkv_kernel(
    const float* __restrict__ h,
    const float* __restrict__ wq, const float* __restrict__ bq,
    const float* __restrict__ wk, const float* __restrict__ bk,
    const float* __restrict__ wv, const float* __restrict__ bv,
    unsigned short* __restrict__ qo, unsigned short* __restrict__ ko,
    unsigned short* __restrict__ vo)
{
    const int TS = 16;
    __shared__ float hl[TS][CC_];
    int blk = blockIdx.x;
    int b  = blk / (S_ / TS);
    int s0 = (blk % (S_ / TS)) * TS;
    int tid = threadIdx.x;

    for (int idx = tid; idx < TS * CC_; idx += 256)
        hl[idx / CC_][idx % CC_] = h[((size_t)b * S_ + s0 + idx / CC_) * CC_ + idx % CC_];
    __syncthreads();

    int col = tid, n = col / HD_, d = col % HD_;
    const float* Ws[3] = {wq, wk, wv};
    const float* Bs[3] = {bq, bk, bv};
    unsigned short* Os[3] = {qo, ko, vo};
#pragma unroll
    for (int m = 0; m < 3; m++) {
        float acc[TS];
        float bias = Bs[m][col];
#pragma unroll
        for (int i = 0; i < TS; i++) acc[i] = bias;
        const float* W = Ws[m];
        for (int kk = 0; kk < CC_; kk++) {
            float w = W[kk * H_ + col];
#pragma unroll
            for (int r = 0; r < TS; r++) acc[r] += hl[r][kk] * w;
        }
        unsigned short* O = Os[m];
        for (int r = 0; r < TS; r++) {
            __hip_bfloat16 bv16 = __float2bfloat16(acc[r]);
            O[(((size_t)b * NH_ + n) * S_ + s0 + r) * HD_ + d] = *(unsigned short*)&bv16;
        }
    }
}

// ---------------------------------------------------------------------------
// Kernel 4: MFMA flash attention. Block = (64 q rows) x (b, head); 4 waves,
// each wave owns 16 q rows. KV tiles of 64 keys staged in LDS (V transposed).
// mfma_f32_16x16x32_bf16: A/B lane l -> row/col l&15, k = (l>>4)*8 + [0..8)
//                         C/D lane l -> col l&15,  row = (l>>4)*4 + reg
// ---------------------------------------------------------------------------
__global__ __launch_bounds__(256) void attn_mfma_kernel(
    const unsigned short* __restrict__ q, const unsigned short* __restrict__ k,
    const unsigned short* __restrict__ v, const float* __restrict__ pvec,
    const int* __restrict__ lenv, float* __restrict__ ctx)
{
    __shared__ short Kt[64][40];      // [key][d], row stride 80B
    __shared__ short Vt[32][72];      // [d][key], row stride 144B
    __shared__ short Pl[4][16][72];   // per-wave P, [q][key], row stride 144B
    __shared__ float pks[64];

    const int tid = threadIdx.x;
    const int wave = tid >> 6, lane = tid & 63;
    const int l15 = lane & 15, l4 = lane >> 4;
    const int qt = blockIdx.x, n = blockIdx.y, b = blockIdx.z;
    const int qw = qt * 64 + wave * 16;
    const int L = lenv[b];

    const size_t head = ((size_t)b * NH_ + n) * S_;
    const unsigned short* qbase = q + head * HD_;
    const unsigned short* kbase = k + head * HD_;
    const unsigned short* vbase = v + head * HD_;

    // Q fragment (held across the whole K loop)
    bf16x8 qf = *(const bf16x8*)(qbase + (size_t)(qw + l15) * HD_ + l4 * 8);

    float pvq[4];
    bool  vq[4];
#pragma unroll
    for (int r = 0; r < 4; r++) {
        int row = qw + l4 * 4 + r;
        pvq[r] = pvec[(size_t)b * S_ + row];
        vq[r] = row < L;
    }

    f32x4 acc0 = {0.f, 0.f, 0.f, 0.f};
    f32x4 acc1 = {0.f, 0.f, 0.f, 0.f};
    float m_r[4], l_r[4];
#pragma unroll
    for (int r = 0; r < 4; r++) { m_r[r] = -1e30f; l_r[r] = 0.f; }

    const int srow = tid >> 2, scg = tid & 3;

    for (int k0 = 0; k0 < S_; k0 += 64) {
        if (k0 >= L) break;  // fully-masked tail contributes exactly 0
        __syncthreads();
        // stage K (row-major, padded) and V^T (transposed, padded)
        bf16x8 kv8 = *(const bf16x8*)(kbase + (size_t)(k0 + srow) * HD_ + scg * 8);
        *(bf16x8*)(&Kt[srow][scg * 8]) = kv8;
        bf16x8 vv8 = *(const bf16x8*)(vbase + (size_t)(k0 + srow) * HD_ + scg * 8);
#pragma unroll
        for (int i = 0; i < 8; i++) Vt[scg * 8 + i][srow] = vv8[i];
        if (tid < 64) pks[tid] = pvec[(size_t)b * S_ + k0 + tid];
        __syncthreads();

        // ---- QK^T: 4 sub-tiles of 16 keys, K=32 each ----
        f32x4 sc[4];
#pragma unroll
        for (int sub = 0; sub < 4; sub++) {
            bf16x8 kf = *(const bf16x8*)(&Kt[sub * 16 + l15][l4 * 8]);
            f32x4 z = {0.f, 0.f, 0.f, 0.f};
            sc[sub] = __builtin_amdgcn_mfma_f32_16x16x32_bf16(qf, kf, z, 0, 0, 0);
        }

        // ---- scale + penalty + mask, row max ----
        float pmx[4];
#pragma unroll
        for (int r = 0; r < 4; r++) pmx[r] = -1e30f;
#pragma unroll
        for (int sub = 0; sub < 4; sub++) {
            int kg = k0 + l15 + 16 * sub;
            bool vk = kg < L;
            float pk = pks[l15 + 16 * sub];
#pragma unroll
            for (int r = 0; r < 4; r++) {
                float s = sc[sub][r] * 0.17677669529663687f;
                if (vk) { if (vq[r]) s -= 0.5f * (pvq[r] + pk); }
                else s = -1e10f;
                sc[sub][r] = s;
                pmx[r] = fmaxf(pmx[r], s);
            }
        }
#pragma unroll
        for (int r = 0; r < 4; r++) {
#pragma unroll
            for (int off = 1; off < 16; off <<= 1)
                pmx[r] = fmaxf(pmx[r], __shfl_xor(pmx[r], off, 64));
        }
        float alpha[4], rs[4];
#pragma unroll
        for (int r = 0; r < 4; r++) {
            float mn = fmaxf(m_r[r], pmx[r]);
            alpha[r] = __expf(m_r[r] - mn);
            m_r[r] = mn;
            rs[r] = 0.f;
        }
        // ---- p = exp(s - m), row sums ----
#pragma unroll
        for (int sub = 0; sub < 4; sub++)
#pragma unroll
            for (int r = 0; r < 4; r++) {
                float p = __expf(sc[sub][r] - m_r[r]);
                sc[sub][r] = p;
                rs[r] += p;
            }
#pragma unroll
        for (int r = 0; r < 4; r++) {
#pragma unroll
            for (int off = 1; off < 16; off <<= 1)
                rs[r] += __shfl_xor(rs[r], off, 64);
            l_r[r] = l_r[r] * alpha[r] + rs[r];
        }
        // ---- P -> LDS (transpose D-layout -> A-layout) ----
#pragma unroll
        for (int sub = 0; sub < 4; sub++)
#pragma unroll
            for (int r = 0; r < 4; r++) {
                __hip_bfloat16 pb = __float2bfloat16(sc[sub][r]);
                Pl[wave][l4 * 4 + r][l15 + 16 * sub] = *(short*)&pb;
            }
        // ---- rescale ctx, then PV: 2 key-blocks x 2 d-halves ----
#pragma unroll
        for (int r = 0; r < 4; r++) { acc0[r] *= alpha[r]; acc1[r] *= alpha[r]; }
#pragma unroll
        for (int kb = 0; kb < 2; kb++) {
            bf16x8 pa = *(const bf16x8*)(&Pl[wave][l15][kb * 32 + l4 * 8]);
            bf16x8 vb0 = *(const bf16x8*)(&Vt[l15][kb * 32 + l4 * 8]);
            acc0 = __builtin_amdgcn_mfma_f32_16x16x32_bf16(pa, vb0, acc0, 0, 0, 0);
            bf16x8 vb1 = *(const bf16x8*)(&Vt[16 + l15][kb * 32 + l4 * 8]);
            acc1 = __builtin_amdgcn_mfma_f32_16x16x32_bf16(pa, vb1, acc1, 0, 0, 0);
        }
    }

    // normalize + write ctx (B,S,H) f32
#pragma unroll
    for (int r = 0; r < 4; r++) {
        int row = qw + l4 * 4 + r;
        float inv = 1.f / l_r[r];
        size_t o = ((size_t)b * S_ + row) * H_ + n * HD_;
        ctx[o + l15]      = acc0[r] * inv;
        ctx[o + 16 + l15] = acc1[r] * inv;
    }
}

// ---------------------------------------------------------------------------
// Kernel 5: fc + residual + LayerNorm (unchanged)
// ---------------------------------------------------------------------------
__global__ __launch_bounds__(256) void fc_ln_kernel(
    const float* __restrict__ ctxv, const float* __restrict__ h,
    const float* __restrict__ fw, const float* __restrict__ fb,
    const float* __restrict__ g, const float* __restrict__ bb,
    float* __restrict__ out)
{
    const int TS = 16;
    __shared__ float cl[TS][CC_];
    int blk = blockIdx.x;
    int b  = blk / (S_ / TS);
    int s0 = (blk % (S_ / TS)) * TS;
    int tid = threadIdx.x;

    for (int idx = tid; idx < TS * CC_; idx += 256)
        cl[idx / CC_][idx % CC_] = ctxv[((size_t)b * S_ + s0 + idx / CC_) * H_ + idx % CC_];
    __syncthreads();

    int col = tid;
    float acc[TS];
    float bias = fb[col];
#pragma unroll
    for (int i = 0; i < TS; i++) acc[i] = bias;
    for (int kk = 0; kk < H_; kk++) {
        float w = fw[kk * CC_ + col];
#pragma unroll
        for (int r2 = 0; r2 < TS; r2++) acc[r2] += cl[r2][kk] * w;
    }
    __syncthreads();
    for (int r2 = 0; r2 < TS; r2++)
        cl[r2][col] = acc[r2] + h[((size_t)b * S_ + s0 + r2) * CC_ + col];
    __syncthreads();

    int wid = tid >> 6, lane = tid & 63;
    for (int r2 = wid * 4; r2 < wid * 4 + 4; r2++) {
        float z0 = cl[r2][lane], z1 = cl[r2][lane + 64];
        float z2 = cl[r2][lane + 128], z3 = cl[r2][lane + 192];
        float s = z0 + z1 + z2 + z3;
#pragma unroll
        for (int off = 32; off > 0; off >>= 1) s += __shfl_xor(s, off, 64);
        float mu = s * (1.f / 256.f);
        float d0 = z0 - mu, d1 = z1 - mu, d2 = z2 - mu, d3 = z3 - mu;
        float vs = d0 * d0 + d1 * d1 + d2 * d2 + d3 * d3;
#pragma unroll
        for (int off = 32; off > 0; off >>= 1) vs += __shfl_xor(vs, off, 64);
        float inv = rsqrtf(vs * (1.f / 256.f) + 1e-5f);
        size_t ro = ((size_t)b * S_ + s0 + r2) * CC_;
#pragma unroll
        for (int i = 0; i < 4; i++) {
            int c = lane + 64 * i;
            float dz = (i == 0) ? d0 : (i == 1) ? d1 : (i == 2) ? d2 : d3;
            out[ro + c] = dz * inv * g[c] + bb[c];
        }
    }
}

// ---------------------------------------------------------------------------
extern "C" void kernel_launch(void* const* d_in, const int* in_sizes, int n_in,
                              void* d_out, int out_size, void* d_ws, size_t ws_size,
                              hipStream_t stream)
{
    const float* x      = (const float*)d_in[0];
    const void*  mask   = d_in[1];
    const float* conv_w = (const float*)d_in[2];
    const float* conv_b = (const float*)d_in[3];
    const float* wq     = (const float*)d_in[4];
    const float* bq     = (const float*)d_in[5];
    const float* wk     = (const float*)d_in[6];
    const float* bk     = (const float*)d_in[7];
    const float* wv     = (const float*)d_in[8];
    const float* bv     = (const float*)d_in[9];
    const float* fc_w   = (const float*)d_in[10];
    const float* fc_b   = (const float*)d_in[11];
    const float* ln_g   = (const float*)d_in[12];
    const float* ln_b   = (const float*)d_in[13];
    const float* gamma  = (const float*)d_in[14];
    const float* stdp   = (const float*)d_in[15];

    char* ws = (char*)d_ws;
    const size_t MB = 1024 * 1024;
    float*          h    = (float*)(ws);                       // 16 MB f32
    unsigned short* qb   = (unsigned short*)(ws + 16 * MB);    // 8 MB bf16
    unsigned short* kb   = (unsigned short*)(ws + 24 * MB);    // 8 MB bf16
    unsigned short* vb   = (unsigned short*)(ws + 32 * MB);    // 8 MB bf16
    float*          ctx  = (float*)(ws + 40 * MB);             // 16 MB f32
    float*          pvec = (float*)(ws + 56 * MB);             // 64 KB
    int*            lenv = (int*)(ws + 56 * MB + 64 * 1024);

    conv_relu_kernel<<<B_ * S_ / 16, 256, 0, stream>>>(x, conv_w, conv_b, h);
    penalty_kernel<<<B_, 256, 0, stream>>>(mask, gamma, stdp, pvec, lenv);
    qkv_kernel<<<B_ * S_ / 16, 256, 0, stream>>>(h, wq, bq, wk, bk, wv, bv, qb, kb, vb);
    dim3 ag(S_ / 64, NH_, B_);
    attn_mfma_kernel<<<ag, 256, 0, stream>>>(qb, kb, vb, pvec, lenv, ctx);
    fc_ln_kernel<<<B_ * S_ / 16, 256, 0, stream>>>(ctx, h, fc_w, fc_b, ln_g, ln_b,
                                                   (float*)d_out);
}

// Round 4
// 281.651 us; speedup vs baseline: 12.8354x; 1.8255x over previous
//
#include <hip/hip_runtime.h>
#include <hip/hip_bf16.h>

#define B_ 8
#define S_ 2048
#define E_ 128
#define CC_ 256
#define H_ 256
#define NH_ 8
#define HD_ 32
#define KW_ 7

typedef __attribute__((ext_vector_type(8))) short bf16x8;
typedef __attribute__((ext_vector_type(4))) float f32x4;

static __device__ __forceinline__ unsigned short f2bf(float f) {
    __hip_bfloat16 h = __float2bfloat16(f);
    return *(unsigned short*)&h;
}
static __device__ __forceinline__ float bf2f(unsigned short u) {
    __hip_bfloat16 h = *(__hip_bfloat16*)&u;
    return __bfloat162float(h);
}

// ---------------------------------------------------------------------------
// Weight reorder kernels: build the exact [col][k] LDS images in bf16.
// ---------------------------------------------------------------------------
// wre2[((kk*4+eb)*256+cc)*32+kl] = conv_w[cc][eb*32+kl][kk]
__global__ __launch_bounds__(256) void reorder_convw(
    const float* __restrict__ cw, unsigned short* __restrict__ wre2)
{
    int i = blockIdx.x * 256 + threadIdx.x;           // < 229376
    int kl = i & 31, cc = (i >> 5) & 255, eb = (i >> 13) & 3, kk = i >> 15;
    wre2[i] = f2bf(cw[cc * (E_ * KW_) + (eb * 32 + kl) * KW_ + kk]);
}
// wqkv2[((m*8+kb)*256+col)*32+kl] = w_m[(kb*32+kl)*256+col]
__global__ __launch_bounds__(256) void reorder_qkvw(
    const float* __restrict__ wq, const float* __restrict__ wk,
    const float* __restrict__ wv, unsigned short* __restrict__ wqkv2)
{
    int i = blockIdx.x * 256 + threadIdx.x;           // < 196608
    int kl = i & 31, col = (i >> 5) & 255, kb = (i >> 13) & 7, m = i >> 16;
    const float* W = (m == 0) ? wq : (m == 1) ? wk : wv;
    wqkv2[i] = f2bf(W[(kb * 32 + kl) * H_ + col]);
}
// wf2[(kb*256+col)*32+kl] = fc_w[(kb*32+kl)*256+col]
__global__ __launch_bounds__(256) void reorder_fcw(
    const float* __restrict__ fw, unsigned short* __restrict__ wf2)
{
    int i = blockIdx.x * 256 + threadIdx.x;           // < 65536
    int kl = i & 31, col = (i >> 5) & 255, kb = i >> 13;
    wf2[i] = f2bf(fw[(kb * 32 + kl) * CC_ + col]);
}

// ---------------------------------------------------------------------------
// penalty vector pvec(B,S) + valid lengths (unchanged)
// ---------------------------------------------------------------------------
__global__ __launch_bounds__(256) void penalty_kernel(
    const void* __restrict__ mask, const float* __restrict__ gamma_p,
    const float* __restrict__ std_p, float* __restrict__ pvec,
    int* __restrict__ lenv)
{
    __shared__ int cnt[256];
    int b = blockIdx.x, tid = threadIdx.x;

    uint32_t w0 = ((const uint32_t*)mask)[0];
    int mode = 0;
    if (w0 == 0x01010101u) mode = 1;
    else if (w0 == 0x3F803F80u) mode = 2;
    else if (w0 == 0x3F800000u) mode = 3;

    int c = 0;
    for (int s = tid; s < S_; s += 256) {
        bool vv;
        size_t i = (size_t)b * S_ + s;
        if (mode == 0)      vv = ((const int*)mask)[i] != 0;
        else if (mode == 1) vv = ((const unsigned char*)mask)[i] != 0;
        else if (mode == 2) vv = (((const unsigned short*)mask)[i] & 0x7FFFu) != 0;
        else                vv = ((const float*)mask)[i] != 0.f;
        c += vv ? 1 : 0;
    }
    cnt[tid] = c;
    __syncthreads();
    for (int off = 128; off > 0; off >>= 1) {
        if (tid < off) cnt[tid] += cnt[tid + off];
        __syncthreads();
    }
    int L = cnt[0];
    if (tid == 0) lenv[b] = L;

    float Lf = (float)L;
    float gamma = gamma_p[0];
    float sd = std_p[0];
    sd = fminf(fmaxf(sd, 0.01f), 0.5f);
    float scale = expf(gamma) - 1.f;
    float inv2s2 = 1.f / (2.f * sd * sd);
    for (int s = tid; s < S_; s += 256) {
        float np = (s + 1.f) / (Lf + 1.f);
        float e = np - 0.5f;
        float base = expf(-(e * e) * inv2s2);
        pvec[(size_t)b * S_ + s] = (s < L) ? base * scale : 0.f;
    }
}

// ---------------------------------------------------------------------------
// Conv1d as 7 shifted GEMMs on MFMA. Block = 64 s-rows x 256 out-ch, 4 waves,
// wave w owns cols w*64..w*64+64 (4 col-tiles) x all 64 rows (4 row-tiles).
// ---------------------------------------------------------------------------
__global__ __launch_bounds__(256) void conv_mfma_kernel(
    const float* __restrict__ x, const unsigned short* __restrict__ wre2,
    const float* __restrict__ cb, unsigned short* __restrict__ hb)
{
    __shared__ short xl[70][136];   // row stride 272B: (68r)%32 -> free
    __shared__ short Bs[256][40];   // row stride 80B:  (20r)%32 -> free
    const int tid = threadIdx.x, wave = tid >> 6, lane = tid & 63;
    const int l15 = lane & 15, l4 = lane >> 4;
    const int s0 = blockIdx.x * 64, b = blockIdx.y;

    // stage x rows s0-3 .. s0+66 (f32 -> bf16)
    for (int idx = tid; idx < 70 * 32; idx += 256) {
        int row = idx >> 5, c4 = idx & 31;
        int pos = s0 - 3 + row;
        float4 v = {0.f, 0.f, 0.f, 0.f};
        if (pos >= 0 && pos < S_)
            v = *(const float4*)(x + ((size_t)b * S_ + pos) * E_ + c4 * 4);
        short* p = &xl[row][c4 * 4];
        p[0] = (short)f2bf(v.x); p[1] = (short)f2bf(v.y);
        p[2] = (short)f2bf(v.z); p[3] = (short)f2bf(v.w);
    }

    f32x4 acc[4][4];
#pragma unroll
    for (int i = 0; i < 4; i++)
#pragma unroll
        for (int j = 0; j < 4; j++) acc[i][j] = (f32x4){0.f, 0.f, 0.f, 0.f};

#pragma unroll 1
    for (int kk = 0; kk < KW_; kk++) {
#pragma unroll 1
        for (int eb = 0; eb < 4; eb++) {
            __syncthreads();
            // stage B: thread t copies row cc=t (32 bf16 = 64B)
            {
                const unsigned short* src = wre2 + (((size_t)(kk * 4 + eb) * 256 + tid) * 32);
#pragma unroll
                for (int j = 0; j < 4; j++)
                    *(bf16x8*)(&Bs[tid][j * 8]) = *(const bf16x8*)(src + j * 8);
            }
            __syncthreads();

            bf16x8 af[4], bfr[4];
#pragma unroll
            for (int rt = 0; rt < 4; rt++)
                af[rt] = *(const bf16x8*)(&xl[rt * 16 + l15 + kk][eb * 32 + l4 * 8]);
#pragma unroll
            for (int ct = 0; ct < 4; ct++)
                bfr[ct] = *(const bf16x8*)(&Bs[wave * 64 + ct * 16 + l15][l4 * 8]);
#pragma unroll
            for (int rt = 0; rt < 4; rt++)
#pragma unroll
                for (int ct = 0; ct < 4; ct++)
                    acc[rt][ct] = __builtin_amdgcn_mfma_f32_16x16x32_bf16(
                        af[rt], bfr[ct], acc[rt][ct], 0, 0, 0);
        }
    }

    // epilogue: bias + relu -> hb bf16
#pragma unroll
    for (int ct = 0; ct < 4; ct++) {
        int col = wave * 64 + ct * 16 + l15;
        float bias = cb[col];
#pragma unroll
        for (int rt = 0; rt < 4; rt++)
#pragma unroll
            for (int r = 0; r < 4; r++) {
                float v0 = acc[rt][ct][r] + bias;
                v0 = v0 > 0.f ? v0 : 0.f;
                int row = s0 + rt * 16 + l4 * 4 + r;
                hb[((size_t)b * S_ + row) * CC_ + col] = f2bf(v0);
            }
    }
}

// ---------------------------------------------------------------------------
// QKV: 3 GEMMs (M=64/block, N=256, K=256) sharing one staged A tile.
// Outputs bf16 (B,NH,S,HD).
// ---------------------------------------------------------------------------
__global__ __launch_bounds__(256) void qkv_mfma_kernel(
    const unsigned short* __restrict__ hb, const unsigned short* __restrict__ wqkv2,
    const float* __restrict__ bq, const float* __restrict__ bk,
    const float* __restrict__ bv,
    unsigned short* __restrict__ qo, unsigned short* __restrict__ ko,
    unsigned short* __restrict__ vo)
{
    __shared__ short Al[64][264];   // row stride 528B -> free
    __shared__ short Bs[256][40];
    const int tid = threadIdx.x, wave = tid >> 6, lane = tid & 63;
    const int l15 = lane & 15, l4 = lane >> 4;
    const int s0 = blockIdx.x * 64, b = blockIdx.y;

    for (int idx = tid; idx < 64 * 32; idx += 256) {
        int row = idx >> 5, c8 = idx & 31;
        *(bf16x8*)(&Al[row][c8 * 8]) =
            *(const bf16x8*)(hb + ((size_t)b * S_ + s0 + row) * CC_ + c8 * 8);
    }

#pragma unroll 1
    for (int m = 0; m < 3; m++) {
        f32x4 acc[4][4];
#pragma unroll
        for (int i = 0; i < 4; i++)
#pragma unroll
            for (int j = 0; j < 4; j++) acc[i][j] = (f32x4){0.f, 0.f, 0.f, 0.f};

#pragma unroll 1
        for (int kb8 = 0; kb8 < 8; kb8++) {
            __syncthreads();
            {
                const unsigned short* src = wqkv2 + (((size_t)(m * 8 + kb8) * 256 + tid) * 32);
#pragma unroll
                for (int j = 0; j < 4; j++)
                    *(bf16x8*)(&Bs[tid][j * 8]) = *(const bf16x8*)(src + j * 8);
            }
            __syncthreads();

            bf16x8 af[4], bfr[4];
#pragma unroll
            for (int rt = 0; rt < 4; rt++)
                af[rt] = *(const bf16x8*)(&Al[rt * 16 + l15][kb8 * 32 + l4 * 8]);
#pragma unroll
            for (int ct = 0; ct < 4; ct++)
                bfr[ct] = *(const bf16x8*)(&Bs[wave * 64 + ct * 16 + l15][l4 * 8]);
#pragma unroll
            for (int rt = 0; rt < 4; rt++)
#pragma unroll
                for (int ct = 0; ct < 4; ct++)
                    acc[rt][ct] = __builtin_amdgcn_mfma_f32_16x16x32_bf16(
                        af[rt], bfr[ct], acc[rt][ct], 0, 0, 0);
        }

        const float* bias_p = (m == 0) ? bq : (m == 1) ? bk : bv;
        unsigned short* O = (m == 0) ? qo : (m == 1) ? ko : vo;
#pragma unroll
        for (int ct = 0; ct < 4; ct++) {
            int col = wave * 64 + ct * 16 + l15;
            float bias = bias_p[col];
            int n = col >> 5, d = col & 31;
#pragma unroll
            for (int rt = 0; rt < 4; rt++)
#pragma unroll
                for (int r = 0; r < 4; r++) {
                    int row = s0 + rt * 16 + l4 * 4 + r;
                    O[(((size_t)b * NH_ + n) * S_ + row) * HD_ + d] =
                        f2bf(acc[rt][ct][r] + bias);
                }
        }
    }
}

// ---------------------------------------------------------------------------
// MFMA flash attention (round-3 structure; ctx output now bf16)
// ---------------------------------------------------------------------------
__global__ __launch_bounds__(256) void attn_mfma_kernel(
    const unsigned short* __restrict__ q, const unsigned short* __restrict__ k,
    const unsigned short* __restrict__ v, const float* __restrict__ pvec,
    const int* __restrict__ lenv, unsigned short* __restrict__ ctxb)
{
    __shared__ short Kt[64][40];
    __shared__ short Vt[32][72];
    __shared__ short Pl[4][16][72];
    __shared__ float pks[64];

    const int tid = threadIdx.x;
    const int wave = tid >> 6, lane = tid & 63;
    const int l15 = lane & 15, l4 = lane >> 4;
    const int qt = blockIdx.x, n = blockIdx.y, b = blockIdx.z;
    const int qw = qt * 64 + wave * 16;
    const int L = lenv[b];

    const size_t head = ((size_t)b * NH_ + n) * S_;
    const unsigned short* qbase = q + head * HD_;
    const unsigned short* kbase = k + head * HD_;
    const unsigned short* vbase = v + head * HD_;

    bf16x8 qf = *(const bf16x8*)(qbase + (size_t)(qw + l15) * HD_ + l4 * 8);

    float pvq[4];
    bool  vq[4];
#pragma unroll
    for (int r = 0; r < 4; r++) {
        int row = qw + l4 * 4 + r;
        pvq[r] = pvec[(size_t)b * S_ + row];
        vq[r] = row < L;
    }

    f32x4 acc0 = {0.f, 0.f, 0.f, 0.f};
    f32x4 acc1 = {0.f, 0.f, 0.f, 0.f};
    float m_r[4], l_r[4];
#pragma unroll
    for (int r = 0; r < 4; r++) { m_r[r] = -1e30f; l_r[r] = 0.f; }

    const int srow = tid >> 2, scg = tid & 3;

    for (int k0 = 0; k0 < S_; k0 += 64) {
        if (k0 >= L) break;
        __syncthreads();
        bf16x8 kv8 = *(const bf16x8*)(kbase + (size_t)(k0 + srow) * HD_ + scg * 8);
        *(bf16x8*)(&Kt[srow][scg * 8]) = kv8;
        bf16x8 vv8 = *(const bf16x8*)(vbase + (size_t)(k0 + srow) * HD_ + scg * 8);
#pragma unroll
        for (int i = 0; i < 8; i++) Vt[scg * 8 + i][srow] = vv8[i];
        if (tid < 64) pks[tid] = pvec[(size_t)b * S_ + k0 + tid];
        __syncthreads();

        f32x4 sc[4];
#pragma unroll
        for (int sub = 0; sub < 4; sub++) {
            bf16x8 kf = *(const bf16x8*)(&Kt[sub * 16 + l15][l4 * 8]);
            f32x4 z = {0.f, 0.f, 0.f, 0.f};
            sc[sub] = __builtin_amdgcn_mfma_f32_16x16x32_bf16(qf, kf, z, 0, 0, 0);
        }

        float pmx[4];
#pragma unroll
        for (int r = 0; r < 4; r++) pmx[r] = -1e30f;
#pragma unroll
        for (int sub = 0; sub < 4; sub++) {
            int kg = k0 + l15 + 16 * sub;
            bool vk = kg < L;
            float pk = pks[l15 + 16 * sub];
#pragma unroll
            for (int r = 0; r < 4; r++) {
                float s = sc[sub][r] * 0.17677669529663687f;
                if (vk) { if (vq[r]) s -= 0.5f * (pvq[r] + pk); }
                else s = -1e10f;
                sc[sub][r] = s;
                pmx[r] = fmaxf(pmx[r], s);
            }
        }
#pragma unroll
        for (int r = 0; r < 4; r++) {
#pragma unroll
            for (int off = 1; off < 16; off <<= 1)
                pmx[r] = fmaxf(pmx[r], __shfl_xor(pmx[r], off, 64));
        }
        float alpha[4], rs[4];
#pragma unroll
        for (int r = 0; r < 4; r++) {
            float mn = fmaxf(m_r[r], pmx[r]);
            alpha[r] = __expf(m_r[r] - mn);
            m_r[r] = mn;
            rs[r] = 0.f;
        }
#pragma unroll
        for (int sub = 0; sub < 4; sub++)
#pragma unroll
            for (int r = 0; r < 4; r++) {
                float p = __expf(sc[sub][r] - m_r[r]);
                sc[sub][r] = p;
                rs[r] += p;
            }
#pragma unroll
        for (int r = 0; r < 4; r++) {
#pragma unroll
            for (int off = 1; off < 16; off <<= 1)
                rs[r] += __shfl_xor(rs[r], off, 64);
            l_r[r] = l_r[r] * alpha[r] + rs[r];
        }
#pragma unroll
        for (int sub = 0; sub < 4; sub++)
#pragma unroll
            for (int r = 0; r < 4; r++)
                Pl[wave][l4 * 4 + r][l15 + 16 * sub] = (short)f2bf(sc[sub][r]);
#pragma unroll
        for (int r = 0; r < 4; r++) { acc0[r] *= alpha[r]; acc1[r] *= alpha[r]; }
#pragma unroll
        for (int kb = 0; kb < 2; kb++) {
            bf16x8 pa = *(const bf16x8*)(&Pl[wave][l15][kb * 32 + l4 * 8]);
            bf16x8 vb0 = *(const bf16x8*)(&Vt[l15][kb * 32 + l4 * 8]);
            acc0 = __builtin_amdgcn_mfma_f32_16x16x32_bf16(pa, vb0, acc0, 0, 0, 0);
            bf16x8 vb1 = *(const bf16x8*)(&Vt[16 + l15][kb * 32 + l4 * 8]);
            acc1 = __builtin_amdgcn_mfma_f32_16x16x32_bf16(pa, vb1, acc1, 0, 0, 0);
        }
    }

#pragma unroll
    for (int r = 0; r < 4; r++) {
        int row = qw + l4 * 4 + r;
        float inv = 1.f / l_r[r];
        size_t o = ((size_t)b * S_ + row) * H_ + n * HD_;
        ctxb[o + l15]      = f2bf(acc0[r] * inv);
        ctxb[o + 16 + l15] = f2bf(acc1[r] * inv);
    }
}

// ---------------------------------------------------------------------------
// FC GEMM + residual + LayerNorm fused. Wave = 16 rows x 256 cols, A in regs.
// ---------------------------------------------------------------------------
__global__ __launch_bounds__(256) void fc_ln_mfma_kernel(
    const unsigned short* __restrict__ ctxb, const unsigned short* __restrict__ hb,
    const unsigned short* __restrict__ wf2, const float* __restrict__ fb,
    const float* __restrict__ g, const float* __restrict__ bbias,
    float* __restrict__ out)
{
    __shared__ short Bs[256][40];
    const int tid = threadIdx.x, wave = tid >> 6, lane = tid & 63;
    const int l15 = lane & 15, l4 = lane >> 4;
    const int s0 = blockIdx.x * 64, b = blockIdx.y;
    const int arow = s0 + wave * 16 + l15;   // this lane's A row

    bf16x8 af[8];
#pragma unroll
    for (int kb = 0; kb < 8; kb++)
        af[kb] = *(const bf16x8*)(ctxb + (size_t)((size_t)b * S_ + arow) * H_ + kb * 32 + l4 * 8);

    f32x4 acc[16];
#pragma unroll
    for (int ct = 0; ct < 16; ct++) acc[ct] = (f32x4){0.f, 0.f, 0.f, 0.f};

#pragma unroll 1
    for (int kb = 0; kb < 8; kb++) {
        __syncthreads();
        {
            const unsigned short* src = wf2 + (((size_t)kb * 256 + tid) * 32);
#pragma unroll
            for (int j = 0; j < 4; j++)
                *(bf16x8*)(&Bs[tid][j * 8]) = *(const bf16x8*)(src + j * 8);
        }
        __syncthreads();
#pragma unroll
        for (int ct = 0; ct < 16; ct++) {
            bf16x8 bfr = *(const bf16x8*)(&Bs[ct * 16 + l15][l4 * 8]);
            acc[ct] = __builtin_amdgcn_mfma_f32_16x16x32_bf16(af[kb], bfr, acc[ct], 0, 0, 0);
        }
    }

    // epilogue: bias + residual + LN (rows = s0 + wave*16 + l4*4 + r)
    float fbias[16];
#pragma unroll
    for (int ct = 0; ct < 16; ct++) fbias[ct] = fb[ct * 16 + l15];

#pragma unroll
    for (int r = 0; r < 4; r++) {
        int row = s0 + wave * 16 + l4 * 4 + r;
        size_t ro = ((size_t)b * S_ + row) * CC_;
        float z[16];
        float sum = 0.f;
#pragma unroll
        for (int ct = 0; ct < 16; ct++) {
            float zz = acc[ct][r] + fbias[ct] + bf2f(hb[ro + ct * 16 + l15]);
            z[ct] = zz;
            sum += zz;
        }
#pragma unroll
        for (int off = 1; off < 16; off <<= 1) sum += __shfl_xor(sum, off, 64);
        float mu = sum * (1.f / 256.f);
        float vs = 0.f;
#pragma unroll
        for (int ct = 0; ct < 16; ct++) {
            float d = z[ct] - mu;
            z[ct] = d;
            vs += d * d;
        }
#pragma unroll
        for (int off = 1; off < 16; off <<= 1) vs += __shfl_xor(vs, off, 64);
        float inv = rsqrtf(vs * (1.f / 256.f) + 1e-5f);
#pragma unroll
        for (int ct = 0; ct < 16; ct++) {
            int col = ct * 16 + l15;
            out[ro + col] = z[ct] * inv * g[col] + bbias[col];
        }
    }
}

// ---------------------------------------------------------------------------
extern "C" void kernel_launch(void* const* d_in, const int* in_sizes, int n_in,
                              void* d_out, int out_size, void* d_ws, size_t ws_size,
                              hipStream_t stream)
{
    const float* x      = (const float*)d_in[0];
    const void*  mask   = d_in[1];
    const float* conv_w = (const float*)d_in[2];
    const float* conv_b = (const float*)d_in[3];
    const float* wq     = (const float*)d_in[4];
    const float* bq     = (const float*)d_in[5];
    const float* wk     = (const float*)d_in[6];
    const float* bk     = (const float*)d_in[7];
    const float* wv     = (const float*)d_in[8];
    const float* bv     = (const float*)d_in[9];
    const float* fc_w   = (const float*)d_in[10];
    const float* fc_b   = (const float*)d_in[11];
    const float* ln_g   = (const float*)d_in[12];
    const float* ln_b   = (const float*)d_in[13];
    const float* gamma  = (const float*)d_in[14];
    const float* stdp   = (const float*)d_in[15];

    char* ws = (char*)d_ws;
    const size_t MB = 1024 * 1024;
    unsigned short* hb    = (unsigned short*)(ws);             // 8 MB bf16
    unsigned short* qb    = (unsigned short*)(ws + 8 * MB);    // 8 MB
    unsigned short* kb    = (unsigned short*)(ws + 16 * MB);   // 8 MB
    unsigned short* vb    = (unsigned short*)(ws + 24 * MB);   // 8 MB
    unsigned short* ctxb  = (unsigned short*)(ws + 32 * MB);   // 8 MB
    float*          pvec  = (float*)(ws + 40 * MB);            // 64 KB
    int*            lenv  = (int*)(ws + 40 * MB + 64 * 1024);
    unsigned short* wre2  = (unsigned short*)(ws + 41 * MB);   // 448 KB
    unsigned short* wqkv2 = (unsigned short*)(ws + 42 * MB);   // 384 KB
    unsigned short* wf2   = (unsigned short*)(ws + 43 * MB);   // 128 KB

    reorder_convw<<<896, 256, 0, stream>>>(conv_w, wre2);
    reorder_qkvw<<<768, 256, 0, stream>>>(wq, wk, wv, wqkv2);
    reorder_fcw<<<256, 256, 0, stream>>>(fc_w, wf2);
    penalty_kernel<<<B_, 256, 0, stream>>>(mask, gamma, stdp, pvec, lenv);

    dim3 g2(S_ / 64, B_);
    conv_mfma_kernel<<<g2, 256, 0, stream>>>(x, wre2, conv_b, hb);
    qkv_mfma_kernel<<<g2, 256, 0, stream>>>(hb, wqkv2, bq, bk, bv, qb, kb, vb);
    dim3 ag(S_ / 64, NH_, B_);
    attn_mfma_kernel<<<ag, 256, 0, stream>>>(qb, kb, vb, pvec, lenv, ctxb);
    fc_ln_mfma_kernel<<<g2, 256, 0, stream>>>(ctxb, hb, wf2, fc_b, ln_g, ln_b,
                                              (float*)d_out);
}

// Round 5
// 263.860 us; speedup vs baseline: 13.7009x; 1.0674x over previous
//
#include <hip/hip_runtime.h>
#include <hip/hip_bf16.h>

#define B_ 8
#define S_ 2048
#define E_ 128
#define CC_ 256
#define H_ 256
#define NH_ 8
#define HD_ 32
#define KW_ 7

typedef __attribute__((ext_vector_type(8))) short bf16x8;
typedef __attribute__((ext_vector_type(4))) float f32x4;

// fold 1/sqrt(HD) * log2(e) into Q so attention works in exp2 domain
#define QSCALE_ (0.17677669529663687f * 1.4426950408889634f)
#define CPEN_   0.7213475204444817f   /* 0.5 * log2(e) */

static __device__ __forceinline__ unsigned short f2bf(float f) {
    __hip_bfloat16 h = __float2bfloat16(f);
    return *(unsigned short*)&h;
}
static __device__ __forceinline__ float bf2f(unsigned short u) {
    __hip_bfloat16 h = *(__hip_bfloat16*)&u;
    return __bfloat162float(h);
}

// ---------------------------------------------------------------------------
// Weight reorder kernels (unchanged)
// ---------------------------------------------------------------------------
__global__ __launch_bounds__(256) void reorder_convw(
    const float* __restrict__ cw, unsigned short* __restrict__ wre2)
{
    int i = blockIdx.x * 256 + threadIdx.x;
    int kl = i & 31, cc = (i >> 5) & 255, eb = (i >> 13) & 3, kk = i >> 15;
    wre2[i] = f2bf(cw[cc * (E_ * KW_) + (eb * 32 + kl) * KW_ + kk]);
}
__global__ __launch_bounds__(256) void reorder_qkvw(
    const float* __restrict__ wq, const float* __restrict__ wk,
    const float* __restrict__ wv, unsigned short* __restrict__ wqkv2)
{
    int i = blockIdx.x * 256 + threadIdx.x;
    int kl = i & 31, col = (i >> 5) & 255, kb = (i >> 13) & 7, m = i >> 16;
    const float* W = (m == 0) ? wq : (m == 1) ? wk : wv;
    wqkv2[i] = f2bf(W[(kb * 32 + kl) * H_ + col]);
}
__global__ __launch_bounds__(256) void reorder_fcw(
    const float* __restrict__ fw, unsigned short* __restrict__ wf2)
{
    int i = blockIdx.x * 256 + threadIdx.x;
    int kl = i & 31, col = (i >> 5) & 255, kb = i >> 13;
    wf2[i] = f2bf(fw[(kb * 32 + kl) * CC_ + col]);
}

// ---------------------------------------------------------------------------
// penalty vector pvec(B,S) + valid lengths (unchanged)
// ---------------------------------------------------------------------------
__global__ __launch_bounds__(256) void penalty_kernel(
    const void* __restrict__ mask, const float* __restrict__ gamma_p,
    const float* __restrict__ std_p, float* __restrict__ pvec,
    int* __restrict__ lenv)
{
    __shared__ int cnt[256];
    int b = blockIdx.x, tid = threadIdx.x;

    uint32_t w0 = ((const uint32_t*)mask)[0];
    int mode = 0;
    if (w0 == 0x01010101u) mode = 1;
    else if (w0 == 0x3F803F80u) mode = 2;
    else if (w0 == 0x3F800000u) mode = 3;

    int c = 0;
    for (int s = tid; s < S_; s += 256) {
        bool vv;
        size_t i = (size_t)b * S_ + s;
        if (mode == 0)      vv = ((const int*)mask)[i] != 0;
        else if (mode == 1) vv = ((const unsigned char*)mask)[i] != 0;
        else if (mode == 2) vv = (((const unsigned short*)mask)[i] & 0x7FFFu) != 0;
        else                vv = ((const float*)mask)[i] != 0.f;
        c += vv ? 1 : 0;
    }
    cnt[tid] = c;
    __syncthreads();
    for (int off = 128; off > 0; off >>= 1) {
        if (tid < off) cnt[tid] += cnt[tid + off];
        __syncthreads();
    }
    int L = cnt[0];
    if (tid == 0) lenv[b] = L;

    float Lf = (float)L;
    float gamma = gamma_p[0];
    float sd = std_p[0];
    sd = fminf(fmaxf(sd, 0.01f), 0.5f);
    float scale = expf(gamma) - 1.f;
    float inv2s2 = 1.f / (2.f * sd * sd);
    for (int s = tid; s < S_; s += 256) {
        float np = (s + 1.f) / (Lf + 1.f);
        float e = np - 0.5f;
        float base = expf(-(e * e) * inv2s2);
        pvec[(size_t)b * S_ + s] = (s < L) ? base * scale : 0.f;
    }
}

// ---------------------------------------------------------------------------
// Conv1d as 7 shifted GEMMs on MFMA (unchanged from round 4)
// ---------------------------------------------------------------------------
__global__ __launch_bounds__(256) void conv_mfma_kernel(
    const float* __restrict__ x, const unsigned short* __restrict__ wre2,
    const float* __restrict__ cb, unsigned short* __restrict__ hb)
{
    __shared__ short xl[70][136];
    __shared__ short Bs[256][40];
    const int tid = threadIdx.x, wave = tid >> 6, lane = tid & 63;
    const int l15 = lane & 15, l4 = lane >> 4;
    const int s0 = blockIdx.x * 64, b = blockIdx.y;

    for (int idx = tid; idx < 70 * 32; idx += 256) {
        int row = idx >> 5, c4 = idx & 31;
        int pos = s0 - 3 + row;
        float4 v = {0.f, 0.f, 0.f, 0.f};
        if (pos >= 0 && pos < S_)
            v = *(const float4*)(x + ((size_t)b * S_ + pos) * E_ + c4 * 4);
        short* p = &xl[row][c4 * 4];
        p[0] = (short)f2bf(v.x); p[1] = (short)f2bf(v.y);
        p[2] = (short)f2bf(v.z); p[3] = (short)f2bf(v.w);
    }

    f32x4 acc[4][4];
#pragma unroll
    for (int i = 0; i < 4; i++)
#pragma unroll
        for (int j = 0; j < 4; j++) acc[i][j] = (f32x4){0.f, 0.f, 0.f, 0.f};

#pragma unroll 1
    for (int kk = 0; kk < KW_; kk++) {
#pragma unroll 1
        for (int eb = 0; eb < 4; eb++) {
            __syncthreads();
            {
                const unsigned short* src = wre2 + (((size_t)(kk * 4 + eb) * 256 + tid) * 32);
#pragma unroll
                for (int j = 0; j < 4; j++)
                    *(bf16x8*)(&Bs[tid][j * 8]) = *(const bf16x8*)(src + j * 8);
            }
            __syncthreads();

            bf16x8 af[4], bfr[4];
#pragma unroll
            for (int rt = 0; rt < 4; rt++)
                af[rt] = *(const bf16x8*)(&xl[rt * 16 + l15 + kk][eb * 32 + l4 * 8]);
#pragma unroll
            for (int ct = 0; ct < 4; ct++)
                bfr[ct] = *(const bf16x8*)(&Bs[wave * 64 + ct * 16 + l15][l4 * 8]);
#pragma unroll
            for (int rt = 0; rt < 4; rt++)
#pragma unroll
                for (int ct = 0; ct < 4; ct++)
                    acc[rt][ct] = __builtin_amdgcn_mfma_f32_16x16x32_bf16(
                        af[rt], bfr[ct], acc[rt][ct], 0, 0, 0);
        }
    }

#pragma unroll
    for (int ct = 0; ct < 4; ct++) {
        int col = wave * 64 + ct * 16 + l15;
        float bias = cb[col];
#pragma unroll
        for (int rt = 0; rt < 4; rt++)
#pragma unroll
            for (int r = 0; r < 4; r++) {
                float v0 = acc[rt][ct][r] + bias;
                v0 = v0 > 0.f ? v0 : 0.f;
                int row = s0 + rt * 16 + l4 * 4 + r;
                hb[((size_t)b * S_ + row) * CC_ + col] = f2bf(v0);
            }
    }
}

// ---------------------------------------------------------------------------
// QKV GEMMs; Q output pre-scaled by 1/sqrt(HD)*log2(e)
// ---------------------------------------------------------------------------
__global__ __launch_bounds__(256) void qkv_mfma_kernel(
    const unsigned short* __restrict__ hb, const unsigned short* __restrict__ wqkv2,
    const float* __restrict__ bq, const float* __restrict__ bk,
    const float* __restrict__ bv,
    unsigned short* __restrict__ qo, unsigned short* __restrict__ ko,
    unsigned short* __restrict__ vo)
{
    __shared__ short Al[64][264];
    __shared__ short Bs[256][40];
    const int tid = threadIdx.x, wave = tid >> 6, lane = tid & 63;
    const int l15 = lane & 15, l4 = lane >> 4;
    const int s0 = blockIdx.x * 64, b = blockIdx.y;

    for (int idx = tid; idx < 64 * 32; idx += 256) {
        int row = idx >> 5, c8 = idx & 31;
        *(bf16x8*)(&Al[row][c8 * 8]) =
            *(const bf16x8*)(hb + ((size_t)b * S_ + s0 + row) * CC_ + c8 * 8);
    }

#pragma unroll 1
    for (int m = 0; m < 3; m++) {
        f32x4 acc[4][4];
#pragma unroll
        for (int i = 0; i < 4; i++)
#pragma unroll
            for (int j = 0; j < 4; j++) acc[i][j] = (f32x4){0.f, 0.f, 0.f, 0.f};

#pragma unroll 1
        for (int kb8 = 0; kb8 < 8; kb8++) {
            __syncthreads();
            {
                const unsigned short* src = wqkv2 + (((size_t)(m * 8 + kb8) * 256 + tid) * 32);
#pragma unroll
                for (int j = 0; j < 4; j++)
                    *(bf16x8*)(&Bs[tid][j * 8]) = *(const bf16x8*)(src + j * 8);
            }
            __syncthreads();

            bf16x8 af[4], bfr[4];
#pragma unroll
            for (int rt = 0; rt < 4; rt++)
                af[rt] = *(const bf16x8*)(&Al[rt * 16 + l15][kb8 * 32 + l4 * 8]);
#pragma unroll
            for (int ct = 0; ct < 4; ct++)
                bfr[ct] = *(const bf16x8*)(&Bs[wave * 64 + ct * 16 + l15][l4 * 8]);
#pragma unroll
            for (int rt = 0; rt < 4; rt++)
#pragma unroll
                for (int ct = 0; ct < 4; ct++)
                    acc[rt][ct] = __builtin_amdgcn_mfma_f32_16x16x32_bf16(
                        af[rt], bfr[ct], acc[rt][ct], 0, 0, 0);
        }

        const float* bias_p = (m == 0) ? bq : (m == 1) ? bk : bv;
        unsigned short* O = (m == 0) ? qo : (m == 1) ? ko : vo;
        const float oscale = (m == 0) ? QSCALE_ : 1.f;
#pragma unroll
        for (int ct = 0; ct < 4; ct++) {
            int col = wave * 64 + ct * 16 + l15;
            float bias = bias_p[col];
            int n = col >> 5, d = col & 31;
#pragma unroll
            for (int rt = 0; rt < 4; rt++)
#pragma unroll
                for (int r = 0; r < 4; r++) {
                    int row = s0 + rt * 16 + l4 * 4 + r;
                    O[(((size_t)b * NH_ + n) * S_ + row) * HD_ + d] =
                        f2bf((acc[rt][ct][r] + bias) * oscale);
                }
        }
    }
}

// ---------------------------------------------------------------------------
// MFMA flash attention, v2: exp2 domain, row-penalty dropped (softmax-
// invariant), column terms in registers, XOR-swizzled Vt/Pl (conflict-free),
// KV tile = 128.
// ---------------------------------------------------------------------------
__global__ __launch_bounds__(256) void attn_mfma_kernel(
    const unsigned short* __restrict__ q, const unsigned short* __restrict__ k,
    const unsigned short* __restrict__ v, const float* __restrict__ pvec,
    const int* __restrict__ lenv, unsigned short* __restrict__ ctxb)
{
    __shared__ short Kt[128][40];     // [key][d]
    __shared__ short Vt[32][136];     // [d][key], key-idx ^= ((d>>3)&3)<<4
    __shared__ short Pl[4][16][136];  // per-wave [q][key], key-idx ^= ((q>>2)&3)<<4
    __shared__ float ctA[128], ctP[128];

    const int tid = threadIdx.x;
    const int wave = tid >> 6, lane = tid & 63;
    const int l15 = lane & 15, l4 = lane >> 4;
    const int qt = blockIdx.x, n = blockIdx.y, b = blockIdx.z;
    const int qw = qt * 64 + wave * 16;
    const int L = lenv[b];

    const size_t head = ((size_t)b * NH_ + n) * S_;
    const unsigned short* qbase = q + head * HD_;
    const unsigned short* kbase = k + head * HD_;
    const unsigned short* vbase = v + head * HD_;

    bf16x8 qf = *(const bf16x8*)(qbase + (size_t)(qw + l15) * HD_ + l4 * 8);

    float vqf[4];
#pragma unroll
    for (int r = 0; r < 4; r++) vqf[r] = (qw + l4 * 4 + r < L) ? 1.f : 0.f;

    f32x4 acc0 = {0.f, 0.f, 0.f, 0.f};
    f32x4 acc1 = {0.f, 0.f, 0.f, 0.f};
    float m_r[4], l_r[4];
#pragma unroll
    for (int r = 0; r < 4; r++) { m_r[r] = -1e30f; l_r[r] = 0.f; }

    const int pswz  = ((l15 >> 2) & 3) << 4;         // P read slot (row=l15)
    const int vswz0 = ((l15 >> 3) & 1) << 4;         // V rows 0..15
    const int vswz1 = (2 + ((l15 >> 3) & 1)) << 4;   // V rows 16..31

    for (int k0 = 0; k0 < S_; k0 += 128) {
        if (k0 >= L) break;
        __syncthreads();
        // stage K + swizzled V^T (2 iterations of 256 threads)
#pragma unroll
        for (int t = tid; t < 512; t += 256) {
            int row = t >> 2, scg = t & 3;
            *(bf16x8*)(&Kt[row][scg * 8]) =
                *(const bf16x8*)(kbase + (size_t)(k0 + row) * HD_ + scg * 8);
            bf16x8 vv8 = *(const bf16x8*)(vbase + (size_t)(k0 + row) * HD_ + scg * 8);
            int cs = row ^ (scg << 4);
#pragma unroll
            for (int i = 0; i < 8; i++) Vt[scg * 8 + i][cs] = vv8[i];
        }
        if (tid < 128) {
            int kg = k0 + tid;
            ctA[tid] = (kg < L) ? 0.f : -1e10f;
            ctP[tid] = -CPEN_ * pvec[(size_t)b * S_ + kg];
        }
        __syncthreads();

        float cA[8], cP[8];
#pragma unroll
        for (int sub = 0; sub < 8; sub++) {
            cA[sub] = ctA[l15 + 16 * sub];
            cP[sub] = ctP[l15 + 16 * sub];
        }

        // ---- QK^T: 8 sub-tiles of 16 keys ----
        f32x4 sc[8];
#pragma unroll
        for (int sub = 0; sub < 8; sub++) {
            bf16x8 kf = *(const bf16x8*)(&Kt[sub * 16 + l15][l4 * 8]);
            f32x4 z = {0.f, 0.f, 0.f, 0.f};
            sc[sub] = __builtin_amdgcn_mfma_f32_16x16x32_bf16(qf, kf, z, 0, 0, 0);
        }

        // ---- column terms + row max ----
        float pmx[4];
#pragma unroll
        for (int r = 0; r < 4; r++) pmx[r] = -1e30f;
#pragma unroll
        for (int sub = 0; sub < 8; sub++)
#pragma unroll
            for (int r = 0; r < 4; r++) {
                float s = sc[sub][r] + cA[sub] + vqf[r] * cP[sub];
                sc[sub][r] = s;
                pmx[r] = fmaxf(pmx[r], s);
            }
#pragma unroll
        for (int r = 0; r < 4; r++) {
#pragma unroll
            for (int off = 1; off < 16; off <<= 1)
                pmx[r] = fmaxf(pmx[r], __shfl_xor(pmx[r], off, 64));
        }
        float alpha[4], rs[4];
#pragma unroll
        for (int r = 0; r < 4; r++) {
            float mn = fmaxf(m_r[r], pmx[r]);
            alpha[r] = exp2f(m_r[r] - mn);
            m_r[r] = mn;
            rs[r] = 0.f;
        }
        // ---- p = exp2(s - m), row sums ----
#pragma unroll
        for (int sub = 0; sub < 8; sub++)
#pragma unroll
            for (int r = 0; r < 4; r++) {
                float p = exp2f(sc[sub][r] - m_r[r]);
                sc[sub][r] = p;
                rs[r] += p;
            }
#pragma unroll
        for (int r = 0; r < 4; r++) {
#pragma unroll
            for (int off = 1; off < 16; off <<= 1)
                rs[r] += __shfl_xor(rs[r], off, 64);
            l_r[r] = l_r[r] * alpha[r] + rs[r];
        }
        // ---- P -> LDS (swizzled) ----
#pragma unroll
        for (int sub = 0; sub < 8; sub++)
#pragma unroll
            for (int r = 0; r < 4; r++)
                Pl[wave][l4 * 4 + r][(l15 + 16 * sub) ^ (l4 << 4)] =
                    (short)f2bf(sc[sub][r]);
        // ---- rescale + PV ----
#pragma unroll
        for (int r = 0; r < 4; r++) { acc0[r] *= alpha[r]; acc1[r] *= alpha[r]; }
#pragma unroll
        for (int kb = 0; kb < 4; kb++) {
            const short* prow = &Pl[wave][l15][0];
            bf16x8 pa = *(const bf16x8*)(prow + ((kb * 32 + l4 * 8) ^ pswz));
            const short* vr0 = &Vt[l15][0];
            bf16x8 vb0 = *(const bf16x8*)(vr0 + ((kb * 32 + l4 * 8) ^ vswz0));
            const short* vr1 = &Vt[16 + l15][0];
            bf16x8 vb1 = *(const bf16x8*)(vr1 + ((kb * 32 + l4 * 8) ^ vswz1));
            acc0 = __builtin_amdgcn_mfma_f32_16x16x32_bf16(pa, vb0, acc0, 0, 0, 0);
            acc1 = __builtin_amdgcn_mfma_f32_16x16x32_bf16(pa, vb1, acc1, 0, 0, 0);
        }
    }

#pragma unroll
    for (int r = 0; r < 4; r++) {
        int row = qw + l4 * 4 + r;
        float inv = 1.f / l_r[r];
        size_t o = ((size_t)b * S_ + row) * H_ + n * HD_;
        ctxb[o + l15]      = f2bf(acc0[r] * inv);
        ctxb[o + 16 + l15] = f2bf(acc1[r] * inv);
    }
}

// ---------------------------------------------------------------------------
// FC GEMM + residual + LayerNorm fused (unchanged from round 4)
// ---------------------------------------------------------------------------
__global__ __launch_bounds__(256) void fc_ln_mfma_kernel(
    const unsigned short* __restrict__ ctxb, const unsigned short* __restrict__ hb,
    const unsigned short* __restrict__ wf2, const float* __restrict__ fb,
    const float* __restrict__ g, const float* __restrict__ bbias,
    float* __restrict__ out)
{
    __shared__ short Bs[256][40];
    const int tid = threadIdx.x, wave = tid >> 6, lane = tid & 63;
    const int l15 = lane & 15, l4 = lane >> 4;
    const int s0 = blockIdx.x * 64, b = blockIdx.y;
    const int arow = s0 + wave * 16 + l15;

    bf16x8 af[8];
#pragma unroll
    for (int kb = 0; kb < 8; kb++)
        af[kb] = *(const bf16x8*)(ctxb + (size_t)((size_t)b * S_ + arow) * H_ + kb * 32 + l4 * 8);

    f32x4 acc[16];
#pragma unroll
    for (int ct = 0; ct < 16; ct++) acc[ct] = (f32x4){0.f, 0.f, 0.f, 0.f};

#pragma unroll 1
    for (int kb = 0; kb < 8; kb++) {
        __syncthreads();
        {
            const unsigned short* src = wf2 + (((size_t)kb * 256 + tid) * 32);
#pragma unroll
            for (int j = 0; j < 4; j++)
                *(bf16x8*)(&Bs[tid][j * 8]) = *(const bf16x8*)(src + j * 8);
        }
        __syncthreads();
#pragma unroll
        for (int ct = 0; ct < 16; ct++) {
            bf16x8 bfr = *(const bf16x8*)(&Bs[ct * 16 + l15][l4 * 8]);
            acc[ct] = __builtin_amdgcn_mfma_f32_16x16x32_bf16(af[kb], bfr, acc[ct], 0, 0, 0);
        }
    }

    float fbias[16];
#pragma unroll
    for (int ct = 0; ct < 16; ct++) fbias[ct] = fb[ct * 16 + l15];

#pragma unroll
    for (int r = 0; r < 4; r++) {
        int row = s0 + wave * 16 + l4 * 4 + r;
        size_t ro = ((size_t)b * S_ + row) * CC_;
        float z[16];
        float sum = 0.f;
#pragma unroll
        for (int ct = 0; ct < 16; ct++) {
            float zz = acc[ct][r] + fbias[ct] + bf2f(hb[ro + ct * 16 + l15]);
            z[ct] = zz;
            sum += zz;
        }
#pragma unroll
        for (int off = 1; off < 16; off <<= 1) sum += __shfl_xor(sum, off, 64);
        float mu = sum * (1.f / 256.f);
        float vs = 0.f;
#pragma unroll
        for (int ct = 0; ct < 16; ct++) {
            float d = z[ct] - mu;
            z[ct] = d;
            vs += d * d;
        }
#pragma unroll
        for (int off = 1; off < 16; off <<= 1) vs += __shfl_xor(vs, off, 64);
        float inv = rsqrtf(vs * (1.f / 256.f) + 1e-5f);
#pragma unroll
        for (int ct = 0; ct < 16; ct++) {
            int col = ct * 16 + l15;
            out[ro + col] = z[ct] * inv * g[col] + bbias[col];
        }
    }
}

// ---------------------------------------------------------------------------
extern "C" void kernel_launch(void* const* d_in, const int* in_sizes, int n_in,
                              void* d_out, int out_size, void* d_ws, size_t ws_size,
                              hipStream_t stream)
{
    const float* x      = (const float*)d_in[0];
    const void*  mask   = d_in[1];
    const float* conv_w = (const float*)d_in[2];
    const float* conv_b = (const float*)d_in[3];
    const float* wq     = (const float*)d_in[4];
    const float* bq     = (const float*)d_in[5];
    const float* wk     = (const float*)d_in[6];
    const float* bk     = (const float*)d_in[7];
    const float* wv     = (const float*)d_in[8];
    const float* bv     = (const float*)d_in[9];
    const float* fc_w   = (const float*)d_in[10];
    const float* fc_b   = (const float*)d_in[11];
    const float* ln_g   = (const float*)d_in[12];
    const float* ln_b   = (const float*)d_in[13];
    const float* gamma  = (const float*)d_in[14];
    const float* stdp   = (const float*)d_in[15];

    char* ws = (char*)d_ws;
    const size_t MB = 1024 * 1024;
    unsigned short* hb    = (unsigned short*)(ws);
    unsigned short* qb    = (unsigned short*)(ws + 8 * MB);
    unsigned short* kb    = (unsigned short*)(ws + 16 * MB);
    unsigned short* vb    = (unsigned short*)(ws + 24 * MB);
    unsigned short* ctxb  = (unsigned short*)(ws + 32 * MB);
    float*          pvec  = (float*)(ws + 40 * MB);
    int*            lenv  = (int*)(ws + 40 * MB + 64 * 1024);
    unsigned short* wre2  = (unsigned short*)(ws + 41 * MB);
    unsigned short* wqkv2 = (unsigned short*)(ws + 42 * MB);
    unsigned short* wf2   = (unsigned short*)(ws + 43 * MB);

    reorder_convw<<<896, 256, 0, stream>>>(conv_w, wre2);
    reorder_qkvw<<<768, 256, 0, stream>>>(wq, wk, wv, wqkv2);
    reorder_fcw<<<256, 256, 0, stream>>>(fc_w, wf2);
    penalty_kernel<<<B_, 256, 0, stream>>>(mask, gamma, stdp, pvec, lenv);

    dim3 g2(S_ / 64, B_);
    conv_mfma_kernel<<<g2, 256, 0, stream>>>(x, wre2, conv_b, hb);
    qkv_mfma_kernel<<<g2, 256, 0, stream>>>(hb, wqkv2, bq, bk, bv, qb, kb, vb);
    dim3 ag(S_ / 64, NH_, B_);
    attn_mfma_kernel<<<ag, 256, 0, stream>>>(qb, kb, vb, pvec, lenv, ctxb);
    fc_ln_mfma_kernel<<<g2, 256, 0, stream>>>(ctxb, hb, wf2, fc_b, ln_g, ln_b,
                                              (float*)d_out);
}

// Round 6
// 234.522 us; speedup vs baseline: 15.4148x; 1.1251x over previous
//
#include <hip/hip_runtime.h>
#include <hip/hip_bf16.h>

#define B_ 8
#define S_ 2048
#define E_ 128
#define CC_ 256
#define H_ 256
#define NH_ 8
#define HD_ 32
#define KW_ 7

typedef __attribute__((ext_vector_type(8))) short bf16x8;
typedef __attribute__((ext_vector_type(4))) float f32x4;
typedef __attribute__((ext_vector_type(16))) float f32x16;

// fold 1/sqrt(HD) * log2(e) into Q so attention works in exp2 domain
#define QSCALE_ (0.17677669529663687f * 1.4426950408889634f)
#define CPEN_   0.7213475204444817f   /* 0.5 * log2(e) */

static __device__ __forceinline__ unsigned short f2bf(float f) {
    __hip_bfloat16 h = __float2bfloat16(f);
    return *(unsigned short*)&h;
}
static __device__ __forceinline__ float bf2f(unsigned short u) {
    __hip_bfloat16 h = *(__hip_bfloat16*)&u;
    return __bfloat162float(h);
}
// v_permlane32_swap: newA = [A.lo | B.lo], newB = [A.hi | B.hi]
static __device__ __forceinline__ void perm32swap(unsigned& a, unsigned& b) {
    asm volatile("s_nop 1\n\tv_permlane32_swap_b32 %0, %1" : "+v"(a), "+v"(b));
}

// ---------------------------------------------------------------------------
// Weight reorder kernels (unchanged)
// ---------------------------------------------------------------------------
__global__ __launch_bounds__(256) void reorder_convw(
    const float* __restrict__ cw, unsigned short* __restrict__ wre2)
{
    int i = blockIdx.x * 256 + threadIdx.x;
    int kl = i & 31, cc = (i >> 5) & 255, eb = (i >> 13) & 3, kk = i >> 15;
    wre2[i] = f2bf(cw[cc * (E_ * KW_) + (eb * 32 + kl) * KW_ + kk]);
}
__global__ __launch_bounds__(256) void reorder_qkvw(
    const float* __restrict__ wq, const float* __restrict__ wk,
    const float* __restrict__ wv, unsigned short* __restrict__ wqkv2)
{
    int i = blockIdx.x * 256 + threadIdx.x;
    int kl = i & 31, col = (i >> 5) & 255, kb = (i >> 13) & 7, m = i >> 16;
    const float* W = (m == 0) ? wq : (m == 1) ? wk : wv;
    wqkv2[i] = f2bf(W[(kb * 32 + kl) * H_ + col]);
}
__global__ __launch_bounds__(256) void reorder_fcw(
    const float* __restrict__ fw, unsigned short* __restrict__ wf2)
{
    int i = blockIdx.x * 256 + threadIdx.x;
    int kl = i & 31, col = (i >> 5) & 255, kb = i >> 13;
    wf2[i] = f2bf(fw[(kb * 32 + kl) * CC_ + col]);
}

// ---------------------------------------------------------------------------
// penalty vector pvec(B,S) + valid lengths (unchanged)
// ---------------------------------------------------------------------------
__global__ __launch_bounds__(256) void penalty_kernel(
    const void* __restrict__ mask, const float* __restrict__ gamma_p,
    const float* __restrict__ std_p, float* __restrict__ pvec,
    int* __restrict__ lenv)
{
    __shared__ int cnt[256];
    int b = blockIdx.x, tid = threadIdx.x;

    uint32_t w0 = ((const uint32_t*)mask)[0];
    int mode = 0;
    if (w0 == 0x01010101u) mode = 1;
    else if (w0 == 0x3F803F80u) mode = 2;
    else if (w0 == 0x3F800000u) mode = 3;

    int c = 0;
    for (int s = tid; s < S_; s += 256) {
        bool vv;
        size_t i = (size_t)b * S_ + s;
        if (mode == 0)      vv = ((const int*)mask)[i] != 0;
        else if (mode == 1) vv = ((const unsigned char*)mask)[i] != 0;
        else if (mode == 2) vv = (((const unsigned short*)mask)[i] & 0x7FFFu) != 0;
        else                vv = ((const float*)mask)[i] != 0.f;
        c += vv ? 1 : 0;
    }
    cnt[tid] = c;
    __syncthreads();
    for (int off = 128; off > 0; off >>= 1) {
        if (tid < off) cnt[tid] += cnt[tid + off];
        __syncthreads();
    }
    int L = cnt[0];
    if (tid == 0) lenv[b] = L;

    float Lf = (float)L;
    float gamma = gamma_p[0];
    float sd = std_p[0];
    sd = fminf(fmaxf(sd, 0.01f), 0.5f);
    float scale = expf(gamma) - 1.f;
    float inv2s2 = 1.f / (2.f * sd * sd);
    for (int s = tid; s < S_; s += 256) {
        float np = (s + 1.f) / (Lf + 1.f);
        float e = np - 0.5f;
        float base = expf(-(e * e) * inv2s2);
        pvec[(size_t)b * S_ + s] = (s < L) ? base * scale : 0.f;
    }
}

// ---------------------------------------------------------------------------
// Conv1d as 7 shifted GEMMs on MFMA (unchanged)
// ---------------------------------------------------------------------------
__global__ __launch_bounds__(256) void conv_mfma_kernel(
    const float* __restrict__ x, const unsigned short* __restrict__ wre2,
    const float* __restrict__ cb, unsigned short* __restrict__ hb)
{
    __shared__ short xl[70][136];
    __shared__ short Bs[256][40];
    const int tid = threadIdx.x, wave = tid >> 6, lane = tid & 63;
    const int l15 = lane & 15, l4 = lane >> 4;
    const int s0 = blockIdx.x * 64, b = blockIdx.y;

    for (int idx = tid; idx < 70 * 32; idx += 256) {
        int row = idx >> 5, c4 = idx & 31;
        int pos = s0 - 3 + row;
        float4 v = {0.f, 0.f, 0.f, 0.f};
        if (pos >= 0 && pos < S_)
            v = *(const float4*)(x + ((size_t)b * S_ + pos) * E_ + c4 * 4);
        short* p = &xl[row][c4 * 4];
        p[0] = (short)f2bf(v.x); p[1] = (short)f2bf(v.y);
        p[2] = (short)f2bf(v.z); p[3] = (short)f2bf(v.w);
    }

    f32x4 acc[4][4];
#pragma unroll
    for (int i = 0; i < 4; i++)
#pragma unroll
        for (int j = 0; j < 4; j++) acc[i][j] = (f32x4){0.f, 0.f, 0.f, 0.f};

#pragma unroll 1
    for (int kk = 0; kk < KW_; kk++) {
#pragma unroll 1
        for (int eb = 0; eb < 4; eb++) {
            __syncthreads();
            {
                const unsigned short* src = wre2 + (((size_t)(kk * 4 + eb) * 256 + tid) * 32);
#pragma unroll
                for (int j = 0; j < 4; j++)
                    *(bf16x8*)(&Bs[tid][j * 8]) = *(const bf16x8*)(src + j * 8);
            }
            __syncthreads();

            bf16x8 af[4], bfr[4];
#pragma unroll
            for (int rt = 0; rt < 4; rt++)
                af[rt] = *(const bf16x8*)(&xl[rt * 16 + l15 + kk][eb * 32 + l4 * 8]);
#pragma unroll
            for (int ct = 0; ct < 4; ct++)
                bfr[ct] = *(const bf16x8*)(&Bs[wave * 64 + ct * 16 + l15][l4 * 8]);
#pragma unroll
            for (int rt = 0; rt < 4; rt++)
#pragma unroll
                for (int ct = 0; ct < 4; ct++)
                    acc[rt][ct] = __builtin_amdgcn_mfma_f32_16x16x32_bf16(
                        af[rt], bfr[ct], acc[rt][ct], 0, 0, 0);
        }
    }

#pragma unroll
    for (int ct = 0; ct < 4; ct++) {
        int col = wave * 64 + ct * 16 + l15;
        float bias = cb[col];
#pragma unroll
        for (int rt = 0; rt < 4; rt++)
#pragma unroll
            for (int r = 0; r < 4; r++) {
                float v0 = acc[rt][ct][r] + bias;
                v0 = v0 > 0.f ? v0 : 0.f;
                int row = s0 + rt * 16 + l4 * 4 + r;
                hb[((size_t)b * S_ + row) * CC_ + col] = f2bf(v0);
            }
    }
}

// ---------------------------------------------------------------------------
// QKV GEMMs; Q output pre-scaled by 1/sqrt(HD)*log2(e)  (unchanged)
// ---------------------------------------------------------------------------
__global__ __launch_bounds__(256) void qkv_mfma_kernel(
    const unsigned short* __restrict__ hb, const unsigned short* __restrict__ wqkv2,
    const float* __restrict__ bq, const float* __restrict__ bk,
    const float* __restrict__ bv,
    unsigned short* __restrict__ qo, unsigned short* __restrict__ ko,
    unsigned short* __restrict__ vo)
{
    __shared__ short Al[64][264];
    __shared__ short Bs[256][40];
    const int tid = threadIdx.x, wave = tid >> 6, lane = tid & 63;
    const int l15 = lane & 15, l4 = lane >> 4;
    const int s0 = blockIdx.x * 64, b = blockIdx.y;

    for (int idx = tid; idx < 64 * 32; idx += 256) {
        int row = idx >> 5, c8 = idx & 31;
        *(bf16x8*)(&Al[row][c8 * 8]) =
            *(const bf16x8*)(hb + ((size_t)b * S_ + s0 + row) * CC_ + c8 * 8);
    }

#pragma unroll 1
    for (int m = 0; m < 3; m++) {
        f32x4 acc[4][4];
#pragma unroll
        for (int i = 0; i < 4; i++)
#pragma unroll
            for (int j = 0; j < 4; j++) acc[i][j] = (f32x4){0.f, 0.f, 0.f, 0.f};

#pragma unroll 1
        for (int kb8 = 0; kb8 < 8; kb8++) {
            __syncthreads();
            {
                const unsigned short* src = wqkv2 + (((size_t)(m * 8 + kb8) * 256 + tid) * 32);
#pragma unroll
                for (int j = 0; j < 4; j++)
                    *(bf16x8*)(&Bs[tid][j * 8]) = *(const bf16x8*)(src + j * 8);
            }
            __syncthreads();

            bf16x8 af[4], bfr[4];
#pragma unroll
            for (int rt = 0; rt < 4; rt++)
                af[rt] = *(const bf16x8*)(&Al[rt * 16 + l15][kb8 * 32 + l4 * 8]);
#pragma unroll
            for (int ct = 0; ct < 4; ct++)
                bfr[ct] = *(const bf16x8*)(&Bs[wave * 64 + ct * 16 + l15][l4 * 8]);
#pragma unroll
            for (int rt = 0; rt < 4; rt++)
#pragma unroll
                for (int ct = 0; ct < 4; ct++)
                    acc[rt][ct] = __builtin_amdgcn_mfma_f32_16x16x32_bf16(
                        af[rt], bfr[ct], acc[rt][ct], 0, 0, 0);
        }

        const float* bias_p = (m == 0) ? bq : (m == 1) ? bk : bv;
        unsigned short* O = (m == 0) ? qo : (m == 1) ? ko : vo;
        const float oscale = (m == 0) ? QSCALE_ : 1.f;
#pragma unroll
        for (int ct = 0; ct < 4; ct++) {
            int col = wave * 64 + ct * 16 + l15;
            float bias = bias_p[col];
            int n = col >> 5, d = col & 31;
#pragma unroll
            for (int rt = 0; rt < 4; rt++)
#pragma unroll
                for (int r = 0; r < 4; r++) {
                    int row = s0 + rt * 16 + l4 * 4 + r;
                    O[(((size_t)b * NH_ + n) * S_ + row) * HD_ + d] =
                        f2bf((acc[rt][ct][r] + bias) * oscale);
                }
        }
    }
}

// ---------------------------------------------------------------------------
// MFMA flash attention v3: swapped-operand 32x32x16, in-register softmax,
// P redistributed via v_permlane32_swap (no LDS round-trip), column terms
// folded into MFMA C-operand. Wave = 32 q-rows; block = 128 q-rows.
// D layout (32x32): col = lane&31, row = (reg&3)+8*(reg>>2)+4*(lane>>5)
// A/B frag:         row/col = lane&31, k = (lane>>5)*8 + j
// ---------------------------------------------------------------------------
__global__ __launch_bounds__(256) void attn_mfma_kernel(
    const unsigned short* __restrict__ q, const unsigned short* __restrict__ k,
    const unsigned short* __restrict__ v, const float* __restrict__ pvec,
    const int* __restrict__ lenv, unsigned short* __restrict__ ctxb)
{
    __shared__ short Kt[128][40];    // [key][d]
    __shared__ short Vt[32][136];    // [d][key], chunk-swizzled
    __shared__ float ctP[128];       // -CPEN * pvec[key]

    const int tid = threadIdx.x;
    const int wave = tid >> 6, lane = tid & 63;
    const int r31 = lane & 31, hi = lane >> 5;
    const int hi8 = hi * 8, hi4 = hi * 4;
    const int n = blockIdx.y, b = blockIdx.z;
    const int qrow = blockIdx.x * 128 + wave * 32 + r31;
    const int L = lenv[b];

    const size_t head = ((size_t)b * NH_ + n) * S_;
    const unsigned short* qbase = q + head * HD_;
    const unsigned short* kbase = k + head * HD_;
    const unsigned short* vbase = v + head * HD_;

    // Q as B-operand: col = q = r31, k(d) = hi*8 + j (two d-halves)
    bf16x8 qf0 = *(const bf16x8*)(qbase + (size_t)qrow * HD_ + hi8);
    bf16x8 qf1 = *(const bf16x8*)(qbase + (size_t)qrow * HD_ + 16 + hi8);
    const float vqf = (qrow < L) ? 1.f : 0.f;

    f32x16 acc;
#pragma unroll
    for (int r = 0; r < 16; r++) acc[r] = 0.f;
    float m_r = -1e30f, l_r = 0.f;

    const int sky = tid >> 1, sdh = (tid & 1) * 16;  // V staging: key, d-half
    const int d7x2 = 2 * (r31 & 7);                  // V read swizzle term

    for (int k0 = 0; k0 < S_; k0 += 128) {
        if (k0 >= L) break;
        __syncthreads();
        {
            // K: straight copy, 2 chunks/thread-pair
            int row = tid >> 1, ch = (tid & 1) * 16;
            *(bf16x8*)(&Kt[row][ch]) =
                *(const bf16x8*)(kbase + (size_t)(k0 + row) * HD_ + ch);
            // V^T with bijective chunk swizzle phi(d,c) = ((c-2(d&7))&7)|(c&8)
            bf16x8 va = *(const bf16x8*)(vbase + (size_t)(k0 + sky) * HD_ + sdh);
            bf16x8 vb = *(const bf16x8*)(vbase + (size_t)(k0 + sky) * HD_ + sdh + 8);
            int c = sky >> 3, k7 = sky & 7;
#pragma unroll
            for (int i = 0; i < 8; i++) {
                int d0 = sdh + i, d1 = sdh + 8 + i;
                Vt[d0][((((c - 2 * (d0 & 7)) & 7) | (c & 8)) << 3) + k7] = va[i];
                Vt[d1][((((c - 2 * (d1 & 7)) & 7) | (c & 8)) << 3) + k7] = vb[i];
            }
            if (tid < 128) ctP[tid] = -CPEN_ * pvec[(size_t)b * S_ + k0 + tid];
        }
        __syncthreads();

        const bool boundary = (k0 + 128 > L);
        f32x16 sc[4];
#pragma unroll
        for (int t = 0; t < 4; t++) {
            bf16x8 kf0 = *(const bf16x8*)(&Kt[t * 32 + r31][hi8]);
            bf16x8 kf1 = *(const bf16x8*)(&Kt[t * 32 + r31][16 + hi8]);
            f32x16 c0;
#pragma unroll
            for (int g = 0; g < 4; g++) {
                f32x4 cp = *(const f32x4*)(&ctP[t * 32 + g * 8 + hi4]);
#pragma unroll
                for (int j = 0; j < 4; j++) c0[g * 4 + j] = vqf * cp[j];
            }
            if (boundary) {
#pragma unroll
                for (int r = 0; r < 16; r++) {
                    int key = k0 + t * 32 + (r & 3) + 8 * (r >> 2) + hi4;
                    if (key >= L) c0[r] = -1e10f;
                }
            }
            f32x16 s1 = __builtin_amdgcn_mfma_f32_32x32x16_bf16(kf0, qf0, c0, 0, 0, 0);
            sc[t] = __builtin_amdgcn_mfma_f32_32x32x16_bf16(kf1, qf1, s1, 0, 0, 0);
        }

        // in-register softmax: one q per lane (lane halves hold disjoint keys)
        float pmx = -1e30f;
#pragma unroll
        for (int t = 0; t < 4; t++)
#pragma unroll
            for (int r = 0; r < 16; r++) pmx = fmaxf(pmx, sc[t][r]);
        pmx = fmaxf(pmx, __shfl_xor(pmx, 32, 64));
        float mn = fmaxf(m_r, pmx);
        float alpha = exp2f(m_r - mn);
        m_r = mn;
        float rs = 0.f;
#pragma unroll
        for (int t = 0; t < 4; t++)
#pragma unroll
            for (int r = 0; r < 16; r++) {
                float p = exp2f(sc[t][r] - mn);
                sc[t][r] = p;
                rs += p;
            }
        rs += __shfl_xor(rs, 32, 64);
        l_r = l_r * alpha + rs;
#pragma unroll
        for (int r = 0; r < 16; r++) acc[r] *= alpha;

        // PV: pack P to bf16 words, permlane-swap into B-frags, 2 MFMA/subtile
#pragma unroll
        for (int t = 0; t < 4; t++) {
            unsigned U00 = (unsigned)f2bf(sc[t][0])  | ((unsigned)f2bf(sc[t][1])  << 16);
            unsigned U01 = (unsigned)f2bf(sc[t][2])  | ((unsigned)f2bf(sc[t][3])  << 16);
            unsigned U10 = (unsigned)f2bf(sc[t][4])  | ((unsigned)f2bf(sc[t][5])  << 16);
            unsigned U11 = (unsigned)f2bf(sc[t][6])  | ((unsigned)f2bf(sc[t][7])  << 16);
            unsigned U20 = (unsigned)f2bf(sc[t][8])  | ((unsigned)f2bf(sc[t][9])  << 16);
            unsigned U21 = (unsigned)f2bf(sc[t][10]) | ((unsigned)f2bf(sc[t][11]) << 16);
            unsigned U30 = (unsigned)f2bf(sc[t][12]) | ((unsigned)f2bf(sc[t][13]) << 16);
            unsigned U31 = (unsigned)f2bf(sc[t][14]) | ((unsigned)f2bf(sc[t][15]) << 16);
            perm32swap(U00, U10);
            perm32swap(U01, U11);
            perm32swap(U20, U30);
            perm32swap(U21, U31);
            union { unsigned u[4]; bf16x8 v8; } pb0, pb1;
            pb0.u[0] = U00; pb0.u[1] = U01; pb0.u[2] = U10; pb0.u[3] = U11;
            pb1.u[0] = U20; pb1.u[1] = U21; pb1.u[2] = U30; pb1.u[3] = U31;

            int c0i = t * 4 + hi, c1i = t * 4 + 2 + hi;
            bf16x8 vf0 = *(const bf16x8*)(&Vt[r31][(((c0i - d7x2) & 7) | (c0i & 8)) << 3]);
            bf16x8 vf1 = *(const bf16x8*)(&Vt[r31][(((c1i - d7x2) & 7) | (c1i & 8)) << 3]);
            acc = __builtin_amdgcn_mfma_f32_32x32x16_bf16(vf0, pb0.v8, acc, 0, 0, 0);
            acc = __builtin_amdgcn_mfma_f32_32x32x16_bf16(vf1, pb1.v8, acc, 0, 0, 0);
        }
    }

    // epilogue: out[d][q] -> ctx row q, d = (r&3)+8*(r>>2)+4*hi; pack pairs
    float inv = 1.f / l_r;
    size_t obase = ((size_t)b * S_ + qrow) * H_ + n * HD_;
#pragma unroll
    for (int g = 0; g < 4; g++)
#pragma unroll
        for (int w = 0; w < 2; w++) {
            unsigned uo = (unsigned)f2bf(acc[g * 4 + w * 2] * inv) |
                          ((unsigned)f2bf(acc[g * 4 + w * 2 + 1] * inv) << 16);
            int d = 8 * g + hi4 + 2 * w;
            *(unsigned*)(ctxb + obase + d) = uo;
        }
}

// ---------------------------------------------------------------------------
// FC GEMM + residual + LayerNorm fused (unchanged)
// ---------------------------------------------------------------------------
__global__ __launch_bounds__(256) void fc_ln_mfma_kernel(
    const unsigned short* __restrict__ ctxb, const unsigned short* __restrict__ hb,
    const unsigned short* __restrict__ wf2, const float* __restrict__ fb,
    const float* __restrict__ g, const float* __restrict__ bbias,
    float* __restrict__ out)
{
    __shared__ short Bs[256][40];
    const int tid = threadIdx.x, wave = tid >> 6, lane = tid & 63;
    const int l15 = lane & 15, l4 = lane >> 4;
    const int s0 = blockIdx.x * 64, b = blockIdx.y;
    const int arow = s0 + wave * 16 + l15;

    bf16x8 af[8];
#pragma unroll
    for (int kb = 0; kb < 8; kb++)
        af[kb] = *(const bf16x8*)(ctxb + (size_t)((size_t)b * S_ + arow) * H_ + kb * 32 + l4 * 8);

    f32x4 acc[16];
#pragma unroll
    for (int ct = 0; ct < 16; ct++) acc[ct] = (f32x4){0.f, 0.f, 0.f, 0.f};

#pragma unroll 1
    for (int kb = 0; kb < 8; kb++) {
        __syncthreads();
        {
            const unsigned short* src = wf2 + (((size_t)kb * 256 + tid) * 32);
#pragma unroll
            for (int j = 0; j < 4; j++)
                *(bf16x8*)(&Bs[tid][j * 8]) = *(const bf16x8*)(src + j * 8);
        }
        __syncthreads();
#pragma unroll
        for (int ct = 0; ct < 16; ct++) {
            bf16x8 bfr = *(const bf16x8*)(&Bs[ct * 16 + l15][l4 * 8]);
            acc[ct] = __builtin_amdgcn_mfma_f32_16x16x32_bf16(af[kb], bfr, acc[ct], 0, 0, 0);
        }
    }

    float fbias[16];
#pragma unroll
    for (int ct = 0; ct < 16; ct++) fbias[ct] = fb[ct * 16 + l15];

#pragma unroll
    for (int r = 0; r < 4; r++) {
        int row = s0 + wave * 16 + l4 * 4 + r;
        size_t ro = ((size_t)b * S_ + row) * CC_;
        float z[16];
        float sum = 0.f;
#pragma unroll
        for (int ct = 0; ct < 16; ct++) {
            float zz = acc[ct][r] + fbias[ct] + bf2f(hb[ro + ct * 16 + l15]);
            z[ct] = zz;
            sum += zz;
        }
#pragma unroll
        for (int off = 1; off < 16; off <<= 1) sum += __shfl_xor(sum, off, 64);
        float mu = sum * (1.f / 256.f);
        float vs = 0.f;
#pragma unroll
        for (int ct = 0; ct < 16; ct++) {
            float d = z[ct] - mu;
            z[ct] = d;
            vs += d * d;
        }
#pragma unroll
        for (int off = 1; off < 16; off <<= 1) vs += __shfl_xor(vs, off, 64);
        float inv = rsqrtf(vs * (1.f / 256.f) + 1e-5f);
#pragma unroll
        for (int ct = 0; ct < 16; ct++) {
            int col = ct * 16 + l15;
            out[ro + col] = z[ct] * inv * g[col] + bbias[col];
        }
    }
}

// ---------------------------------------------------------------------------
extern "C" void kernel_launch(void* const* d_in, const int* in_sizes, int n_in,
                              void* d_out, int out_size, void* d_ws, size_t ws_size,
                              hipStream_t stream)
{
    const float* x      = (const float*)d_in[0];
    const void*  mask   = d_in[1];
    const float* conv_w = (const float*)d_in[2];
    const float* conv_b = (const float*)d_in[3];
    const float* wq     = (const float*)d_in[4];
    const float* bq     = (const float*)d_in[5];
    const float* wk     = (const float*)d_in[6];
    const float* bk     = (const float*)d_in[7];
    const float* wv     = (const float*)d_in[8];
    const float* bv     = (const float*)d_in[9];
    const float* fc_w   = (const float*)d_in[10];
    const float* fc_b   = (const float*)d_in[11];
    const float* ln_g   = (const float*)d_in[12];
    const float* ln_b   = (const float*)d_in[13];
    const float* gamma  = (const float*)d_in[14];
    const float* stdp   = (const float*)d_in[15];

    char* ws = (char*)d_ws;
    const size_t MB = 1024 * 1024;
    unsigned short* hb    = (unsigned short*)(ws);
    unsigned short* qb    = (unsigned short*)(ws + 8 * MB);
    unsigned short* kb    = (unsigned short*)(ws + 16 * MB);
    unsigned short* vb    = (unsigned short*)(ws + 24 * MB);
    unsigned short* ctxb  = (unsigned short*)(ws + 32 * MB);
    float*          pvec  = (float*)(ws + 40 * MB);
    int*            lenv  = (int*)(ws + 40 * MB + 64 * 1024);
    unsigned short* wre2  = (unsigned short*)(ws + 41 * MB);
    unsigned short* wqkv2 = (unsigned short*)(ws + 42 * MB);
    unsigned short* wf2   = (unsigned short*)(ws + 43 * MB);

    reorder_convw<<<896, 256, 0, stream>>>(conv_w, wre2);
    reorder_qkvw<<<768, 256, 0, stream>>>(wq, wk, wv, wqkv2);
    reorder_fcw<<<256, 256, 0, stream>>>(fc_w, wf2);
    penalty_kernel<<<B_, 256, 0, stream>>>(mask, gamma, stdp, pvec, lenv);

    dim3 g2(S_ / 64, B_);
    conv_mfma_kernel<<<g2, 256, 0, stream>>>(x, wre2, conv_b, hb);
    qkv_mfma_kernel<<<g2, 256, 0, stream>>>(hb, wqkv2, bq, bk, bv, qb, kb, vb);
    dim3 ag(S_ / 128, NH_, B_);
    attn_mfma_kernel<<<ag, 256, 0, stream>>>(qb, kb, vb, pvec, lenv, ctxb);
    fc_ln_mfma_kernel<<<g2, 256, 0, stream>>>(ctxb, hb, wf2, fc_b, ln_g, ln_b,
                                              (float*)d_out);
}

// Round 7
// 200.571 us; speedup vs baseline: 18.0241x; 1.1693x over previous
//
#include <hip/hip_runtime.h>
#include <hip/hip_bf16.h>

#define B_ 8
#define S_ 2048
#define E_ 128
#define CC_ 256
#define H_ 256
#define NH_ 8
#define HD_ 32
#define KW_ 7

typedef __attribute__((ext_vector_type(8))) short bf16x8;
typedef __attribute__((ext_vector_type(4))) float f32x4;
typedef __attribute__((ext_vector_type(16))) float f32x16;

// fold 1/sqrt(HD) * log2(e) into Q so attention works in exp2 domain
#define QSCALE_ (0.17677669529663687f * 1.4426950408889634f)
#define CPEN_   0.7213475204444817f   /* 0.5 * log2(e) */

static __device__ __forceinline__ unsigned short f2bf(float f) {
    __hip_bfloat16 h = __float2bfloat16(f);
    return *(unsigned short*)&h;
}
static __device__ __forceinline__ float bf2f(unsigned short u) {
    __hip_bfloat16 h = *(__hip_bfloat16*)&u;
    return __bfloat162float(h);
}
// v_permlane32_swap: newA = [A.lo | B.lo], newB = [A.hi | B.hi]
static __device__ __forceinline__ void perm32swap(unsigned& a, unsigned& b) {
    asm volatile("s_nop 1\n\tv_permlane32_swap_b32 %0, %1" : "+v"(a), "+v"(b));
}

// ---------------------------------------------------------------------------
// Weight reorder kernels (unchanged)
// ---------------------------------------------------------------------------
__global__ __launch_bounds__(256) void reorder_convw(
    const float* __restrict__ cw, unsigned short* __restrict__ wre2)
{
    int i = blockIdx.x * 256 + threadIdx.x;
    int kl = i & 31, cc = (i >> 5) & 255, eb = (i >> 13) & 3, kk = i >> 15;
    wre2[i] = f2bf(cw[cc * (E_ * KW_) + (eb * 32 + kl) * KW_ + kk]);
}
__global__ __launch_bounds__(256) void reorder_qkvw(
    const float* __restrict__ wq, const float* __restrict__ wk,
    const float* __restrict__ wv, unsigned short* __restrict__ wqkv2)
{
    int i = blockIdx.x * 256 + threadIdx.x;
    int kl = i & 31, col = (i >> 5) & 255, kb = (i >> 13) & 7, m = i >> 16;
    const float* W = (m == 0) ? wq : (m == 1) ? wk : wv;
    wqkv2[i] = f2bf(W[(kb * 32 + kl) * H_ + col]);
}
__global__ __launch_bounds__(256) void reorder_fcw(
    const float* __restrict__ fw, unsigned short* __restrict__ wf2)
{
    int i = blockIdx.x * 256 + threadIdx.x;
    int kl = i & 31, col = (i >> 5) & 255, kb = i >> 13;
    wf2[i] = f2bf(fw[(kb * 32 + kl) * CC_ + col]);
}

// ---------------------------------------------------------------------------
// penalty vector pvec(B,S) + valid lengths (unchanged)
// ---------------------------------------------------------------------------
__global__ __launch_bounds__(256) void penalty_kernel(
    const void* __restrict__ mask, const float* __restrict__ gamma_p,
    const float* __restrict__ std_p, float* __restrict__ pvec,
    int* __restrict__ lenv)
{
    __shared__ int cnt[256];
    int b = blockIdx.x, tid = threadIdx.x;

    uint32_t w0 = ((const uint32_t*)mask)[0];
    int mode = 0;
    if (w0 == 0x01010101u) mode = 1;
    else if (w0 == 0x3F803F80u) mode = 2;
    else if (w0 == 0x3F800000u) mode = 3;

    int c = 0;
    for (int s = tid; s < S_; s += 256) {
        bool vv;
        size_t i = (size_t)b * S_ + s;
        if (mode == 0)      vv = ((const int*)mask)[i] != 0;
        else if (mode == 1) vv = ((const unsigned char*)mask)[i] != 0;
        else if (mode == 2) vv = (((const unsigned short*)mask)[i] & 0x7FFFu) != 0;
        else                vv = ((const float*)mask)[i] != 0.f;
        c += vv ? 1 : 0;
    }
    cnt[tid] = c;
    __syncthreads();
    for (int off = 128; off > 0; off >>= 1) {
        if (tid < off) cnt[tid] += cnt[tid + off];
        __syncthreads();
    }
    int L = cnt[0];
    if (tid == 0) lenv[b] = L;

    float Lf = (float)L;
    float gamma = gamma_p[0];
    float sd = std_p[0];
    sd = fminf(fmaxf(sd, 0.01f), 0.5f);
    float scale = expf(gamma) - 1.f;
    float inv2s2 = 1.f / (2.f * sd * sd);
    for (int s = tid; s < S_; s += 256) {
        float np = (s + 1.f) / (Lf + 1.f);
        float e = np - 0.5f;
        float base = expf(-(e * e) * inv2s2);
        pvec[(size_t)b * S_ + s] = (s < L) ? base * scale : 0.f;
    }
}

// ---------------------------------------------------------------------------
// Conv1d as 7 shifted GEMMs on MFMA. B read directly from reordered global
// (L2-resident, fully coalesced 1KB/wave) — no B LDS, no K-loop barriers.
// ---------------------------------------------------------------------------
__global__ __launch_bounds__(256) void conv_mfma_kernel(
    const float* __restrict__ x, const unsigned short* __restrict__ wre2,
    const float* __restrict__ cb, unsigned short* __restrict__ hb)
{
    __shared__ short xl[70][136];
    const int tid = threadIdx.x, wave = tid >> 6, lane = tid & 63;
    const int l15 = lane & 15, l4 = lane >> 4;
    const int s0 = blockIdx.x * 64, b = blockIdx.y;

    for (int idx = tid; idx < 70 * 32; idx += 256) {
        int row = idx >> 5, c4 = idx & 31;
        int pos = s0 - 3 + row;
        float4 v = {0.f, 0.f, 0.f, 0.f};
        if (pos >= 0 && pos < S_)
            v = *(const float4*)(x + ((size_t)b * S_ + pos) * E_ + c4 * 4);
        short* p = &xl[row][c4 * 4];
        p[0] = (short)f2bf(v.x); p[1] = (short)f2bf(v.y);
        p[2] = (short)f2bf(v.z); p[3] = (short)f2bf(v.w);
    }
    __syncthreads();

    f32x4 acc[4][4];
#pragma unroll
    for (int i = 0; i < 4; i++)
#pragma unroll
        for (int j = 0; j < 4; j++) acc[i][j] = (f32x4){0.f, 0.f, 0.f, 0.f};

#pragma unroll 1
    for (int kk = 0; kk < KW_; kk++) {
#pragma unroll
        for (int eb = 0; eb < 4; eb++) {
            const unsigned short* wp =
                wre2 + (((size_t)(kk * 4 + eb) * 256 + wave * 64 + l15) * 32) + l4 * 8;
            bf16x8 af[4], bfr[4];
#pragma unroll
            for (int ct = 0; ct < 4; ct++)
                bfr[ct] = *(const bf16x8*)(wp + ct * 512);
#pragma unroll
            for (int rt = 0; rt < 4; rt++)
                af[rt] = *(const bf16x8*)(&xl[rt * 16 + l15 + kk][eb * 32 + l4 * 8]);
#pragma unroll
            for (int rt = 0; rt < 4; rt++)
#pragma unroll
                for (int ct = 0; ct < 4; ct++)
                    acc[rt][ct] = __builtin_amdgcn_mfma_f32_16x16x32_bf16(
                        af[rt], bfr[ct], acc[rt][ct], 0, 0, 0);
        }
    }

#pragma unroll
    for (int ct = 0; ct < 4; ct++) {
        int col = wave * 64 + ct * 16 + l15;
        float bias = cb[col];
#pragma unroll
        for (int rt = 0; rt < 4; rt++)
#pragma unroll
            for (int r = 0; r < 4; r++) {
                float v0 = acc[rt][ct][r] + bias;
                v0 = v0 > 0.f ? v0 : 0.f;
                int row = s0 + rt * 16 + l4 * 4 + r;
                hb[((size_t)b * S_ + row) * CC_ + col] = f2bf(v0);
            }
    }
}

// ---------------------------------------------------------------------------
// QKV GEMMs; B direct from global, A staged once. Q pre-scaled.
// ---------------------------------------------------------------------------
__global__ __launch_bounds__(256) void qkv_mfma_kernel(
    const unsigned short* __restrict__ hb, const unsigned short* __restrict__ wqkv2,
    const float* __restrict__ bq, const float* __restrict__ bk,
    const float* __restrict__ bv,
    unsigned short* __restrict__ qo, unsigned short* __restrict__ ko,
    unsigned short* __restrict__ vo)
{
    __shared__ short Al[64][264];
    const int tid = threadIdx.x, wave = tid >> 6, lane = tid & 63;
    const int l15 = lane & 15, l4 = lane >> 4;
    const int s0 = blockIdx.x * 64, b = blockIdx.y;

    for (int idx = tid; idx < 64 * 32; idx += 256) {
        int row = idx >> 5, c8 = idx & 31;
        *(bf16x8*)(&Al[row][c8 * 8]) =
            *(const bf16x8*)(hb + ((size_t)b * S_ + s0 + row) * CC_ + c8 * 8);
    }
    __syncthreads();

#pragma unroll 1
    for (int m = 0; m < 3; m++) {
        f32x4 acc[4][4];
#pragma unroll
        for (int i = 0; i < 4; i++)
#pragma unroll
            for (int j = 0; j < 4; j++) acc[i][j] = (f32x4){0.f, 0.f, 0.f, 0.f};

#pragma unroll 1
        for (int kb8 = 0; kb8 < 8; kb8++) {
            const unsigned short* wp =
                wqkv2 + (((size_t)(m * 8 + kb8) * 256 + wave * 64 + l15) * 32) + l4 * 8;
            bf16x8 af[4], bfr[4];
#pragma unroll
            for (int ct = 0; ct < 4; ct++)
                bfr[ct] = *(const bf16x8*)(wp + ct * 512);
#pragma unroll
            for (int rt = 0; rt < 4; rt++)
                af[rt] = *(const bf16x8*)(&Al[rt * 16 + l15][kb8 * 32 + l4 * 8]);
#pragma unroll
            for (int rt = 0; rt < 4; rt++)
#pragma unroll
                for (int ct = 0; ct < 4; ct++)
                    acc[rt][ct] = __builtin_amdgcn_mfma_f32_16x16x32_bf16(
                        af[rt], bfr[ct], acc[rt][ct], 0, 0, 0);
        }

        const float* bias_p = (m == 0) ? bq : (m == 1) ? bk : bv;
        unsigned short* O = (m == 0) ? qo : (m == 1) ? ko : vo;
        const float oscale = (m == 0) ? QSCALE_ : 1.f;
#pragma unroll
        for (int ct = 0; ct < 4; ct++) {
            int col = wave * 64 + ct * 16 + l15;
            float bias = bias_p[col];
            int n = col >> 5, d = col & 31;
#pragma unroll
            for (int rt = 0; rt < 4; rt++)
#pragma unroll
                for (int r = 0; r < 4; r++) {
                    int row = s0 + rt * 16 + l4 * 4 + r;
                    O[(((size_t)b * NH_ + n) * S_ + row) * HD_ + d] =
                        f2bf((acc[rt][ct][r] + bias) * oscale);
                }
        }
    }
}

// ---------------------------------------------------------------------------
// MFMA flash attention v4: double-buffered async staging (1 barrier/tile),
// mask+penalty pre-staged into 2-row LDS table (per-lane row select),
// defer-max, setprio around MFMA, in-register softmax + permlane P.
// ---------------------------------------------------------------------------
__global__ __launch_bounds__(256) void attn_mfma_kernel(
    const unsigned short* __restrict__ q, const unsigned short* __restrict__ k,
    const unsigned short* __restrict__ v, const float* __restrict__ pvec,
    const int* __restrict__ lenv, unsigned short* __restrict__ ctxb)
{
    __shared__ short Kt[2][128][40];
    __shared__ short Vt[2][32][136];
    __shared__ __align__(16) float ctC[2][2][128];  // [buf][mask | mask+pen][key]

    const int tid = threadIdx.x;
    const int wave = tid >> 6, lane = tid & 63;
    const int r31 = lane & 31, hi = lane >> 5;
    const int hi8 = hi * 8, hi4 = hi * 4;
    const int n = blockIdx.y, b = blockIdx.z;
    const int qrow = blockIdx.x * 128 + wave * 32 + r31;
    const int L = lenv[b];
    const int nt = (L + 127) >> 7;

    const size_t head = ((size_t)b * NH_ + n) * S_;
    const unsigned short* qbase = q + head * HD_;
    const unsigned short* kbase = k + head * HD_;
    const unsigned short* vbase = v + head * HD_;

    bf16x8 qf0 = *(const bf16x8*)(qbase + (size_t)qrow * HD_ + hi8);
    bf16x8 qf1 = *(const bf16x8*)(qbase + (size_t)qrow * HD_ + 16 + hi8);
    const int crow = (qrow < L) ? 1 : 0;

    f32x16 acc;
#pragma unroll
    for (int r = 0; r < 16; r++) acc[r] = 0.f;
    float m_r = -1e30f, l_r = 0.f;

    const int krow = tid >> 1, kch = (tid & 1) * 16;  // staging coords (K and V)
    const int d7x2 = 2 * (r31 & 7);                   // V read swizzle term
    const int vc = krow >> 3, vk7 = krow & 7;         // V write swizzle terms

    // staging registers
    bf16x8 kreg0, kreg1, va, vb;
    float pvr = 0.f;

    // ---- prologue: stage tile 0 ----
    kreg0 = *(const bf16x8*)(kbase + (size_t)krow * HD_ + kch);
    kreg1 = *(const bf16x8*)(kbase + (size_t)krow * HD_ + kch + 8);
    va    = *(const bf16x8*)(vbase + (size_t)krow * HD_ + kch);
    vb    = *(const bf16x8*)(vbase + (size_t)krow * HD_ + kch + 8);
    if (tid < 128) pvr = pvec[(size_t)b * S_ + tid];
    {
        *(bf16x8*)(&Kt[0][krow][kch])     = kreg0;
        *(bf16x8*)(&Kt[0][krow][kch + 8]) = kreg1;
#pragma unroll
        for (int i = 0; i < 8; i++) {
            int d0 = kch + i, d1 = kch + 8 + i;
            Vt[0][d0][((((vc - 2 * (d0 & 7)) & 7) | (vc & 8)) << 3) + vk7] = va[i];
            Vt[0][d1][((((vc - 2 * (d1 & 7)) & 7) | (vc & 8)) << 3) + vk7] = vb[i];
        }
        if (tid < 128) {
            bool vkk = tid < L;
            ctC[0][0][tid] = vkk ? 0.f : -1e10f;
            ctC[0][1][tid] = vkk ? (-CPEN_ * pvr) : -1e10f;
        }
    }
    __syncthreads();

#pragma unroll 1
    for (int t = 0; t < nt; t++) {
        const int cur = t & 1;
        const int knext = (t + 1) << 7;
        const bool more = (t + 1 < nt);

        // ---- ISSUE next tile's global loads (latency hidden under compute) ----
        if (more) {
            kreg0 = *(const bf16x8*)(kbase + (size_t)(knext + krow) * HD_ + kch);
            kreg1 = *(const bf16x8*)(kbase + (size_t)(knext + krow) * HD_ + kch + 8);
            va    = *(const bf16x8*)(vbase + (size_t)(knext + krow) * HD_ + kch);
            vb    = *(const bf16x8*)(vbase + (size_t)(knext + krow) * HD_ + kch + 8);
            if (tid < 128) pvr = pvec[(size_t)b * S_ + knext + tid];
        }

        // ---- QK^T: 4 subtiles of 32 keys, colterm via C-operand ----
        __builtin_amdgcn_s_setprio(1);
        f32x16 sc[4];
#pragma unroll
        for (int t4 = 0; t4 < 4; t4++) {
            bf16x8 kf0 = *(const bf16x8*)(&Kt[cur][t4 * 32 + r31][hi8]);
            bf16x8 kf1 = *(const bf16x8*)(&Kt[cur][t4 * 32 + r31][16 + hi8]);
            f32x16 c0;
#pragma unroll
            for (int g = 0; g < 4; g++) {
                f32x4 cp = *(const f32x4*)(&ctC[cur][crow][t4 * 32 + g * 8 + hi4]);
#pragma unroll
                for (int j = 0; j < 4; j++) c0[g * 4 + j] = cp[j];
            }
            f32x16 s1 = __builtin_amdgcn_mfma_f32_32x32x16_bf16(kf0, qf0, c0, 0, 0, 0);
            sc[t4] = __builtin_amdgcn_mfma_f32_32x32x16_bf16(kf1, qf1, s1, 0, 0, 0);
        }
        __builtin_amdgcn_s_setprio(0);

        // ---- row max (max3-fusable pairs) ----
        float pmx = -1e30f;
#pragma unroll
        for (int t4 = 0; t4 < 4; t4++)
#pragma unroll
            for (int r = 0; r < 16; r += 2)
                pmx = fmaxf(pmx, fmaxf(sc[t4][r], sc[t4][r + 1]));
        pmx = fmaxf(pmx, __shfl_xor(pmx, 32, 64));

        // ---- defer-max: skip rescale when max growth <= 8 (log2 domain) ----
        float alpha = 1.f;
        if (!__all(pmx <= m_r + 8.f)) {
            float mn = fmaxf(m_r, pmx);
            alpha = exp2f(m_r - mn);
            m_r = mn;
#pragma unroll
            for (int r = 0; r < 16; r++) acc[r] *= alpha;
        }

        // ---- p = exp2(s - m), sum, pack to bf16 + permlane redistribute ----
        float rs = 0.f;
        unsigned pk[4][8];
#pragma unroll
        for (int t4 = 0; t4 < 4; t4++) {
            float p[16];
#pragma unroll
            for (int r = 0; r < 16; r++) {
                p[r] = exp2f(sc[t4][r] - m_r);
                rs += p[r];
            }
            unsigned U00 = (unsigned)f2bf(p[0])  | ((unsigned)f2bf(p[1])  << 16);
            unsigned U01 = (unsigned)f2bf(p[2])  | ((unsigned)f2bf(p[3])  << 16);
            unsigned U10 = (unsigned)f2bf(p[4])  | ((unsigned)f2bf(p[5])  << 16);
            unsigned U11 = (unsigned)f2bf(p[6])  | ((unsigned)f2bf(p[7])  << 16);
            unsigned U20 = (unsigned)f2bf(p[8])  | ((unsigned)f2bf(p[9])  << 16);
            unsigned U21 = (unsigned)f2bf(p[10]) | ((unsigned)f2bf(p[11]) << 16);
            unsigned U30 = (unsigned)f2bf(p[12]) | ((unsigned)f2bf(p[13]) << 16);
            unsigned U31 = (unsigned)f2bf(p[14]) | ((unsigned)f2bf(p[15]) << 16);
            perm32swap(U00, U10);
            perm32swap(U01, U11);
            perm32swap(U20, U30);
            perm32swap(U21, U31);
            pk[t4][0] = U00; pk[t4][1] = U01; pk[t4][2] = U10; pk[t4][3] = U11;
            pk[t4][4] = U20; pk[t4][5] = U21; pk[t4][6] = U30; pk[t4][7] = U31;
        }
        rs += __shfl_xor(rs, 32, 64);
        l_r = l_r * alpha + rs;

        // ---- PV ----
        __builtin_amdgcn_s_setprio(1);
#pragma unroll
        for (int t4 = 0; t4 < 4; t4++) {
            union { unsigned u[4]; bf16x8 v8; } pb0, pb1;
            pb0.u[0] = pk[t4][0]; pb0.u[1] = pk[t4][1];
            pb0.u[2] = pk[t4][2]; pb0.u[3] = pk[t4][3];
            pb1.u[0] = pk[t4][4]; pb1.u[1] = pk[t4][5];
            pb1.u[2] = pk[t4][6]; pb1.u[3] = pk[t4][7];
            int c0i = t4 * 4 + hi, c1i = t4 * 4 + 2 + hi;
            bf16x8 vf0 = *(const bf16x8*)(&Vt[cur][r31][(((c0i - d7x2) & 7) | (c0i & 8)) << 3]);
            bf16x8 vf1 = *(const bf16x8*)(&Vt[cur][r31][(((c1i - d7x2) & 7) | (c1i & 8)) << 3]);
            acc = __builtin_amdgcn_mfma_f32_32x32x16_bf16(vf0, pb0.v8, acc, 0, 0, 0);
            acc = __builtin_amdgcn_mfma_f32_32x32x16_bf16(vf1, pb1.v8, acc, 0, 0, 0);
        }
        __builtin_amdgcn_s_setprio(0);

        // ---- WRITE next tile into the other buffer, single barrier ----
        if (more) {
            const int nxt = cur ^ 1;
            *(bf16x8*)(&Kt[nxt][krow][kch])     = kreg0;
            *(bf16x8*)(&Kt[nxt][krow][kch + 8]) = kreg1;
#pragma unroll
            for (int i = 0; i < 8; i++) {
                int d0 = kch + i, d1 = kch + 8 + i;
                Vt[nxt][d0][((((vc - 2 * (d0 & 7)) & 7) | (vc & 8)) << 3) + vk7] = va[i];
                Vt[nxt][d1][((((vc - 2 * (d1 & 7)) & 7) | (vc & 8)) << 3) + vk7] = vb[i];
            }
            if (tid < 128) {
                bool vkk = (knext + tid) < L;
                ctC[nxt][0][tid] = vkk ? 0.f : -1e10f;
                ctC[nxt][1][tid] = vkk ? (-CPEN_ * pvr) : -1e10f;
            }
            __syncthreads();
        }
    }

    // epilogue: out[d][q] -> ctx row q
    float inv = 1.f / l_r;
    size_t obase = ((size_t)b * S_ + qrow) * H_ + n * HD_;
#pragma unroll
    for (int g = 0; g < 4; g++)
#pragma unroll
        for (int w = 0; w < 2; w++) {
            unsigned uo = (unsigned)f2bf(acc[g * 4 + w * 2] * inv) |
                          ((unsigned)f2bf(acc[g * 4 + w * 2 + 1] * inv) << 16);
            int d = 8 * g + hi4 + 2 * w;
            *(unsigned*)(ctxb + obase + d) = uo;
        }
}

// ---------------------------------------------------------------------------
// FC GEMM + residual + LayerNorm fused. B direct from global; zero barriers.
// ---------------------------------------------------------------------------
__global__ __launch_bounds__(256) void fc_ln_mfma_kernel(
    const unsigned short* __restrict__ ctxb, const unsigned short* __restrict__ hb,
    const unsigned short* __restrict__ wf2, const float* __restrict__ fb,
    const float* __restrict__ g, const float* __restrict__ bbias,
    float* __restrict__ out)
{
    const int tid = threadIdx.x, wave = tid >> 6, lane = tid & 63;
    const int l15 = lane & 15, l4 = lane >> 4;
    const int s0 = blockIdx.x * 64, b = blockIdx.y;
    const int arow = s0 + wave * 16 + l15;

    bf16x8 af[8];
#pragma unroll
    for (int kb = 0; kb < 8; kb++)
        af[kb] = *(const bf16x8*)(ctxb + (size_t)((size_t)b * S_ + arow) * H_ + kb * 32 + l4 * 8);

    f32x4 acc[16];
#pragma unroll
    for (int ct = 0; ct < 16; ct++) acc[ct] = (f32x4){0.f, 0.f, 0.f, 0.f};

#pragma unroll 1
    for (int kb = 0; kb < 8; kb++) {
        const unsigned short* wp = wf2 + ((size_t)kb * 256 + l15) * 32 + l4 * 8;
#pragma unroll
        for (int ct = 0; ct < 16; ct++) {
            bf16x8 bfr = *(const bf16x8*)(wp + ct * 512);
            acc[ct] = __builtin_amdgcn_mfma_f32_16x16x32_bf16(af[kb], bfr, acc[ct], 0, 0, 0);
        }
    }

    float fbias[16];
#pragma unroll
    for (int ct = 0; ct < 16; ct++) fbias[ct] = fb[ct * 16 + l15];

#pragma unroll
    for (int r = 0; r < 4; r++) {
        int row = s0 + wave * 16 + l4 * 4 + r;
        size_t ro = ((size_t)b * S_ + row) * CC_;
        float z[16];
        float sum = 0.f;
#pragma unroll
        for (int ct = 0; ct < 16; ct++) {
            float zz = acc[ct][r] + fbias[ct] + bf2f(hb[ro + ct * 16 + l15]);
            z[ct] = zz;
            sum += zz;
        }
#pragma unroll
        for (int off = 1; off < 16; off <<= 1) sum += __shfl_xor(sum, off, 64);
        float mu = sum * (1.f / 256.f);
        float vs = 0.f;
#pragma unroll
        for (int ct = 0; ct < 16; ct++) {
            float d = z[ct] - mu;
            z[ct] = d;
            vs += d * d;
        }
#pragma unroll
        for (int off = 1; off < 16; off <<= 1) vs += __shfl_xor(vs, off, 64);
        float inv = rsqrtf(vs * (1.f / 256.f) + 1e-5f);
#pragma unroll
        for (int ct = 0; ct < 16; ct++) {
            int col = ct * 16 + l15;
            out[ro + col] = z[ct] * inv * g[col] + bbias[col];
        }
    }
}

// ---------------------------------------------------------------------------
extern "C" void kernel_launch(void* const* d_in, const int* in_sizes, int n_in,
                              void* d_out, int out_size, void* d_ws, size_t ws_size,
                              hipStream_t stream)
{
    const float* x      = (const float*)d_in[0];
    const void*  mask   = d_in[1];
    const float* conv_w = (const float*)d_in[2];
    const float* conv_b = (const float*)d_in[3];
    const float* wq     = (const float*)d_in[4];
    const float* bq     = (const float*)d_in[5];
    const float* wk     = (const float*)d_in[6];
    const float* bk     = (const float*)d_in[7];
    const float* wv     = (const float*)d_in[8];
    const float* bv     = (const float*)d_in[9];
    const float* fc_w   = (const float*)d_in[10];
    const float* fc_b   = (const float*)d_in[11];
    const float* ln_g   = (const float*)d_in[12];
    const float* ln_b   = (const float*)d_in[13];
    const float* gamma  = (const float*)d_in[14];
    const float* stdp   = (const float*)d_in[15];

    char* ws = (char*)d_ws;
    const size_t MB = 1024 * 1024;
    unsigned short* hb    = (unsigned short*)(ws);
    unsigned short* qb    = (unsigned short*)(ws + 8 * MB);
    unsigned short* kb    = (unsigned short*)(ws + 16 * MB);
    unsigned short* vb    = (unsigned short*)(ws + 24 * MB);
    unsigned short* ctxb  = (unsigned short*)(ws + 32 * MB);
    float*          pvec  = (float*)(ws + 40 * MB);
    int*            lenv  = (int*)(ws + 40 * MB + 64 * 1024);
    unsigned short* wre2  = (unsigned short*)(ws + 41 * MB);
    unsigned short* wqkv2 = (unsigned short*)(ws + 42 * MB);
    unsigned short* wf2   = (unsigned short*)(ws + 43 * MB);

    reorder_convw<<<896, 256, 0, stream>>>(conv_w, wre2);
    reorder_qkvw<<<768, 256, 0, stream>>>(wq, wk, wv, wqkv2);
    reorder_fcw<<<256, 256, 0, stream>>>(fc_w, wf2);
    penalty_kernel<<<B_, 256, 0, stream>>>(mask, gamma, stdp, pvec, lenv);

    dim3 g2(S_ / 64, B_);
    conv_mfma_kernel<<<g2, 256, 0, stream>>>(x, wre2, conv_b, hb);
    qkv_mfma_kernel<<<g2, 256, 0, stream>>>(hb, wqkv2, bq, bk, bv, qb, kb, vb);
    dim3 ag(S_ / 128, NH_, B_);
    attn_mfma_kernel<<<ag, 256, 0, stream>>>(qb, kb, vb, pvec, lenv, ctxb);
    fc_ln_mfma_kernel<<<g2, 256, 0, stream>>>(ctxb, hb, wf2, fc_b, ln_g, ln_b,
                                              (float*)d_out);
}